// Round 1
// baseline (1575.984 us; speedup 1.0000x reference)
//
#include <hip/hip_runtime.h>
#include <hip/hip_bf16.h>
#include <cstdint>

// DiT block: B=8, N=1024, HID=1024, NH=16, HD=64, MLP=4096.
// Strategy: all big GEMMs via bf16 MFMA 16x16x32 (fp32 accum), weights
// transpose-converted to bf16 [N][K] once per launch; fp32 VALU attention
// (correctness-first, MFMA flash in a later round).

typedef __bf16 bf16;
typedef __attribute__((ext_vector_type(8))) __bf16 bf16x8;
typedef __attribute__((ext_vector_type(4))) __bf16 bf16x4;
typedef __attribute__((ext_vector_type(4))) float f32x4;

#define SEQ   1024
#define NHID  1024
#define NHEAD 16
#define HDIM  64
#define MROWS 8192          // B*SEQ
#define CMS   6144          // cmod row stride

// ---------------------------------------------------------------------------
// Transpose + fp32->bf16 convert:  src [K][N] fp32  ->  dst [N][K] bf16
// ---------------------------------------------------------------------------
__global__ __launch_bounds__(256) void transpose_conv(
    const float* __restrict__ src, bf16* __restrict__ dst, int K, int N)
{
  __shared__ float tile[32][33];
  int n0 = blockIdx.x * 32, k0 = blockIdx.y * 32;
  int tx = threadIdx.x & 31, ty = threadIdx.x >> 5;   // ty in 0..7
#pragma unroll
  for (int i = 0; i < 32; i += 8)
    tile[ty + i][tx] = src[(size_t)(k0 + ty + i) * N + n0 + tx];
  __syncthreads();
#pragma unroll
  for (int i = 0; i < 32; i += 8)
    dst[(size_t)(n0 + ty + i) * K + k0 + tx] = (bf16)tile[tx][ty + i];
}

// ---------------------------------------------------------------------------
// cmod = silu(c) @ w_ada + b_ada      c:[8][1024]  w_ada:[1024][6144]
// grid (24, 8), 256 threads
// ---------------------------------------------------------------------------
__global__ __launch_bounds__(256) void ada_kernel(
    const float* __restrict__ c, const float* __restrict__ w_ada,
    const float* __restrict__ b_ada, float* __restrict__ cmod)
{
  __shared__ float cs[1024];
  int b = blockIdx.y;
  int col = blockIdx.x * 256 + threadIdx.x;
  for (int i = threadIdx.x; i < 1024; i += 256) {
    float cv = c[b * 1024 + i];
    cs[i] = cv / (1.0f + __expf(-cv));
  }
  __syncthreads();
  float acc = b_ada[col];
#pragma unroll 8
  for (int kk = 0; kk < 1024; kk++)
    acc += cs[kk] * w_ada[(size_t)kk * CMS + col];
  cmod[b * CMS + col] = acc;
}

// ---------------------------------------------------------------------------
// LayerNorm (no affine) + modulate -> bf16.  One block per row.
// out = ln(x) * (1 + cmod[b][sc_off+col]) + cmod[b][sh_off+col]
// ---------------------------------------------------------------------------
__global__ __launch_bounds__(256) void ln_mod(
    const float* __restrict__ x, const float* __restrict__ cmod,
    bf16* __restrict__ out, int sh_off, int sc_off)
{
  int row = blockIdx.x, b = row >> 10, tid = threadIdx.x;
  const float4* xr = (const float4*)(x + (size_t)row * NHID);
  float4 v = xr[tid];
  float s  = v.x + v.y + v.z + v.w;
  float s2 = v.x * v.x + v.y * v.y + v.z * v.z + v.w * v.w;
#pragma unroll
  for (int off = 32; off; off >>= 1) {
    s  += __shfl_xor(s, off);
    s2 += __shfl_xor(s2, off);
  }
  __shared__ float red1[4], red2[4];
  int wave = tid >> 6, lane = tid & 63;
  if (lane == 0) { red1[wave] = s; red2[wave] = s2; }
  __syncthreads();
  float S  = red1[0] + red1[1] + red1[2] + red1[3];
  float S2 = red2[0] + red2[1] + red2[2] + red2[3];
  float mean = S * (1.0f / NHID);
  float var  = S2 * (1.0f / NHID) - mean * mean;
  float rs   = rsqrtf(var + 1e-6f);
  const float4* shp = (const float4*)(cmod + b * CMS + sh_off);
  const float4* scp = (const float4*)(cmod + b * CMS + sc_off);
  float4 sh4 = shp[tid], sc4 = scp[tid];
  bf16x4 o4;
  o4[0] = (bf16)((v.x - mean) * rs * (1.0f + sc4.x) + sh4.x);
  o4[1] = (bf16)((v.y - mean) * rs * (1.0f + sc4.y) + sh4.y);
  o4[2] = (bf16)((v.z - mean) * rs * (1.0f + sc4.z) + sh4.z);
  o4[3] = (bf16)((v.w - mean) * rs * (1.0f + sc4.w) + sh4.w);
  *(bf16x4*)(out + (size_t)row * NHID + tid * 4) = o4;
}

// ---------------------------------------------------------------------------
// GEMM: C[M][N] = A[M][K](bf16) @ Bt[N][K](bf16)^T + bias, fused epilogues.
// 128x128 tile, BK=64, 4 waves (2x2 of 64x64), mfma 16x16x32 bf16.
// LDS chunks XOR-swizzled (c ^ (row&7)) -> 16B aligned, <=2-way banks.
// EPI: 0 = bf16 out (QKV)   1 = fp32 out = resid + gate*val (WO)
//      2 = bf16 gelu (W1)   3 = fp32 out = resid + gate*val (W2/final)
// ---------------------------------------------------------------------------
template <int EPI>
__global__ __launch_bounds__(256) void gemm_bt(
    const bf16* __restrict__ A, const bf16* __restrict__ Bt,
    const float* __restrict__ bias,
    bf16* __restrict__ outb, float* __restrict__ outf,
    const float* __restrict__ cmod, int gate_off,
    const float* __restrict__ resid,
    int N, int K)
{
  __shared__ __align__(16) bf16 As[128 * 64];
  __shared__ __align__(16) bf16 Bs[128 * 64];
  const int tid = threadIdx.x;
  const int bm = blockIdx.y * 128, bn = blockIdx.x * 128;
  const int wave = tid >> 6, lane = tid & 63;
  const int quad = lane >> 4, l16 = lane & 15;
  const int wm = (wave >> 1) * 64, wn = (wave & 1) * 64;

  f32x4 acc[4][4];
#pragma unroll
  for (int i = 0; i < 4; i++)
#pragma unroll
    for (int j = 0; j < 4; j++) acc[i][j] = (f32x4)0.0f;

  for (int k0 = 0; k0 < K; k0 += 64) {
#pragma unroll
    for (int i = 0; i < 4; i++) {
      int id = tid + i * 256;          // 1024 chunks of 16B
      int r = id >> 3, cc = id & 7;
      *(uint4*)(As + r * 64 + ((cc ^ (r & 7)) * 8)) =
          *(const uint4*)(A + (size_t)(bm + r) * K + k0 + cc * 8);
      *(uint4*)(Bs + r * 64 + ((cc ^ (r & 7)) * 8)) =
          *(const uint4*)(Bt + (size_t)(bn + r) * K + k0 + cc * 8);
    }
    __syncthreads();
#pragma unroll
    for (int kk = 0; kk < 2; kk++) {
      bf16x8 af[4], bfr[4];
#pragma unroll
      for (int t = 0; t < 4; t++) {
        int ra = wm + t * 16 + l16;
        int rb = wn + t * 16 + l16;
        int cc = kk * 4 + quad;
        af[t]  = *(const bf16x8*)(As + ra * 64 + ((cc ^ (ra & 7)) * 8));
        bfr[t] = *(const bf16x8*)(Bs + rb * 64 + ((cc ^ (rb & 7)) * 8));
      }
#pragma unroll
      for (int mt = 0; mt < 4; mt++)
#pragma unroll
        for (int nt = 0; nt < 4; nt++)
          acc[mt][nt] = __builtin_amdgcn_mfma_f32_16x16x32_bf16(
              af[mt], bfr[nt], acc[mt][nt], 0, 0, 0);
    }
    __syncthreads();
  }

#pragma unroll
  for (int mt = 0; mt < 4; mt++) {
#pragma unroll
    for (int nt = 0; nt < 4; nt++) {
      int col = bn + wn + nt * 16 + l16;
      float bcol = bias[col];
#pragma unroll
      for (int r = 0; r < 4; r++) {
        int row = bm + wm + mt * 16 + quad * 4 + r;
        float val = acc[mt][nt][r] + bcol;
        if (EPI == 0) {
          outb[(size_t)row * N + col] = (bf16)val;
        } else if (EPI == 1 || EPI == 3) {
          int bb = row >> 10;
          float g = cmod[bb * CMS + gate_off + col];
          outf[(size_t)row * N + col] =
              resid[(size_t)row * N + col] + g * val;
        } else {  // EPI == 2: exact GELU
          float ge = 0.5f * val * (1.0f + erff(val * 0.70710678118f));
          outb[(size_t)row * N + col] = (bf16)ge;
        }
      }
    }
  }
}

// ---------------------------------------------------------------------------
// Attention (fp32 VALU, online softmax). Block = 256 thr = 4 waves,
// handles 16 q rows of one (b,h); wave -> 4 q rows. K/V tiles of 64 keys
// staged in LDS (XOR-swizzled). S phase: lane = key. PV phase: lane = d.
// ---------------------------------------------------------------------------
__global__ __launch_bounds__(256) void attn_kernel(
    const bf16* __restrict__ q, const bf16* __restrict__ k,
    const bf16* __restrict__ v, bf16* __restrict__ o)
{
  __shared__ __align__(16) bf16 Ks[64 * 64];
  __shared__ __align__(16) bf16 Vs[64 * 64];
  __shared__ __align__(16) float qs[16 * 64];
  __shared__ float4 pbuf[4 * 64];   // [wave][key]

  int bid = blockIdx.x;
  int qt = bid & 63;
  int h  = (bid >> 6) & 15;
  int b  = bid >> 10;
  int tid = threadIdx.x, wave = tid >> 6, lane = tid & 63;
  int qbase = qt * 16;

  const bf16* qbh = q + ((size_t)(b * SEQ + qbase)) * NHID + h * HDIM;
  const bf16* kbh = k + ((size_t)b * SEQ) * NHID + h * HDIM;
  const bf16* vbh = v + ((size_t)b * SEQ) * NHID + h * HDIM;

#pragma unroll
  for (int i = 0; i < 4; i++) {
    int id = tid + i * 256;
    int r = id >> 6, d = id & 63;
    qs[r * 64 + d] = (float)qbh[(size_t)r * NHID + d];
  }

  float m[4], l[4], O[4];
#pragma unroll
  for (int r = 0; r < 4; r++) { m[r] = -1e30f; l[r] = 0.0f; O[r] = 0.0f; }

  for (int kt = 0; kt < 16; kt++) {
    __syncthreads();   // protect prior-iter LDS reads (also covers qs at kt=0)
#pragma unroll
    for (int i = 0; i < 2; i++) {
      int id = tid + i * 256;          // 512 chunks each for K and V
      int r = id >> 3, cc = id & 7;
      *(uint4*)(Ks + r * 64 + ((cc ^ (r & 7)) * 8)) =
          *(const uint4*)(kbh + (size_t)(kt * 64 + r) * NHID + cc * 8);
      *(uint4*)(Vs + r * 64 + ((cc ^ (r & 7)) * 8)) =
          *(const uint4*)(vbh + (size_t)(kt * 64 + r) * NHID + cc * 8);
    }
    __syncthreads();

    // ---- S phase: this lane owns key j for this wave's 4 q rows
    int j = lane;
    float sarr[4] = {0.0f, 0.0f, 0.0f, 0.0f};
#pragma unroll
    for (int cc = 0; cc < 8; cc++) {
      bf16x8 kv = *(const bf16x8*)(Ks + j * 64 + ((cc ^ (j & 7)) * 8));
      float kf[8];
#pragma unroll
      for (int t = 0; t < 8; t++) kf[t] = (float)kv[t];
#pragma unroll
      for (int r = 0; r < 4; r++) {
        const float4* qp = (const float4*)(qs + (wave * 4 + r) * 64 + cc * 8);
        float4 qa = qp[0], qb4 = qp[1];
        sarr[r] += qa.x * kf[0] + qa.y * kf[1] + qa.z * kf[2] + qa.w * kf[3]
                 + qb4.x * kf[4] + qb4.y * kf[5] + qb4.z * kf[6] + qb4.w * kf[7];
      }
    }
    float4 pv4;
    float alpha[4];
#pragma unroll
    for (int r = 0; r < 4; r++) {
      float s = sarr[r] * (1.0f / 64.0f);
      float tm = s;
#pragma unroll
      for (int off = 32; off; off >>= 1) tm = fmaxf(tm, __shfl_xor(tm, off));
      float mn = fmaxf(m[r], tm);
      float p = __expf(s - mn);
      float ps = p;
#pragma unroll
      for (int off = 32; off; off >>= 1) ps += __shfl_xor(ps, off);
      alpha[r] = __expf(m[r] - mn);
      m[r] = mn;
      l[r] = l[r] * alpha[r] + ps;
      ((float*)&pv4)[r] = p;
    }
    pbuf[wave * 64 + j] = pv4;
    __syncthreads();

    // ---- PV phase: this lane owns output dim d
    int d = lane;
#pragma unroll
    for (int r = 0; r < 4; r++) O[r] *= alpha[r];
    for (int jj = 0; jj < 64; jj++) {
      float vv = (float)Vs[jj * 64 + (((d >> 3) ^ (jj & 7)) * 8) + (d & 7)];
      float4 p4 = pbuf[wave * 64 + jj];
      O[0] += p4.x * vv; O[1] += p4.y * vv;
      O[2] += p4.z * vv; O[3] += p4.w * vv;
    }
  }

  int d = lane;
  bf16* obh = o + ((size_t)(b * SEQ + qbase + wave * 4)) * NHID + h * HDIM;
#pragma unroll
  for (int r = 0; r < 4; r++)
    obh[(size_t)r * NHID + d] = (bf16)(O[r] / l[r]);
}

// ---------------------------------------------------------------------------
// Workspace layout (bytes). Total ~136.2 MiB.
// ---------------------------------------------------------------------------
#define OFF_CMOD 0u
#define OFF_WQT  196608u
#define OFF_WKT  (OFF_WQT + 2097152u)
#define OFF_WVT  (OFF_WKT + 2097152u)
#define OFF_WOT  (OFF_WVT + 2097152u)
#define OFF_W1T  (OFF_WOT + 2097152u)
#define OFF_W2T  (OFF_W1T + 8388608u)
#define OFF_X2   (OFF_W2T + 8388608u)
#define OFF_XM2  (OFF_X2  + 33554432u)
#define OFF_POOL (OFF_XM2 + 16777216u)
// pool (67.1 MB): xm @ +0, q @ +16M, k @ +32M, v @ +48M.
// o aliases xm (dead after QKV GEMMs); h aliases whole pool (q/k/v/o dead).

extern "C" void kernel_launch(void* const* d_in, const int* in_sizes, int n_in,
                              void* d_out, int out_size, void* d_ws, size_t ws_size,
                              hipStream_t stream)
{
  const float* x     = (const float*)d_in[0];
  const float* c     = (const float*)d_in[1];
  const float* w_ada = (const float*)d_in[2];
  const float* b_ada = (const float*)d_in[3];
  const float* wq = (const float*)d_in[4];  const float* bq = (const float*)d_in[5];
  const float* wk = (const float*)d_in[6];  const float* bk = (const float*)d_in[7];
  const float* wv = (const float*)d_in[8];  const float* bv = (const float*)d_in[9];
  const float* wo = (const float*)d_in[10]; const float* bo = (const float*)d_in[11];
  const float* w1 = (const float*)d_in[12]; const float* b1 = (const float*)d_in[13];
  const float* w2 = (const float*)d_in[14]; const float* b2 = (const float*)d_in[15];
  float* out = (float*)d_out;
  char* ws = (char*)d_ws;

  float* cmod = (float*)(ws + OFF_CMOD);
  bf16* wqT = (bf16*)(ws + OFF_WQT);
  bf16* wkT = (bf16*)(ws + OFF_WKT);
  bf16* wvT = (bf16*)(ws + OFF_WVT);
  bf16* woT = (bf16*)(ws + OFF_WOT);
  bf16* w1T = (bf16*)(ws + OFF_W1T);
  bf16* w2T = (bf16*)(ws + OFF_W2T);
  float* x2 = (float*)(ws + OFF_X2);
  bf16* xm2 = (bf16*)(ws + OFF_XM2);
  bf16* xm  = (bf16*)(ws + OFF_POOL);
  bf16* qb  = (bf16*)(ws + OFF_POOL + 16777216u);
  bf16* kb  = (bf16*)(ws + OFF_POOL + 33554432u);
  bf16* vb  = (bf16*)(ws + OFF_POOL + 50331648u);
  bf16* ob  = xm;   // alias
  bf16* hb  = xm;   // alias (covers 64 MB of pool)

  // weight transposes (fp32 [K][N] -> bf16 [N][K])
  transpose_conv<<<dim3(32, 32), 256, 0, stream>>>(wq, wqT, 1024, 1024);
  transpose_conv<<<dim3(32, 32), 256, 0, stream>>>(wk, wkT, 1024, 1024);
  transpose_conv<<<dim3(32, 32), 256, 0, stream>>>(wv, wvT, 1024, 1024);
  transpose_conv<<<dim3(32, 32), 256, 0, stream>>>(wo, woT, 1024, 1024);
  transpose_conv<<<dim3(128, 32), 256, 0, stream>>>(w1, w1T, 1024, 4096);
  transpose_conv<<<dim3(32, 128), 256, 0, stream>>>(w2, w2T, 4096, 1024);

  ada_kernel<<<dim3(24, 8), 256, 0, stream>>>(c, w_ada, b_ada, cmod);

  // ln1 + modulate (sh_msa @ 0, sc_msa @ 1024)
  ln_mod<<<8192, 256, 0, stream>>>(x, cmod, xm, 0, 1024);

  // QKV
  gemm_bt<0><<<dim3(8, 64), 256, 0, stream>>>(xm, wqT, bq, qb, nullptr,
                                              nullptr, 0, nullptr, 1024, 1024);
  gemm_bt<0><<<dim3(8, 64), 256, 0, stream>>>(xm, wkT, bk, kb, nullptr,
                                              nullptr, 0, nullptr, 1024, 1024);
  gemm_bt<0><<<dim3(8, 64), 256, 0, stream>>>(xm, wvT, bv, vb, nullptr,
                                              nullptr, 0, nullptr, 1024, 1024);

  attn_kernel<<<8192, 256, 0, stream>>>(qb, kb, vb, ob);

  // x2 = x + g_msa * (o @ wo + bo)      (g_msa @ 2048)
  gemm_bt<1><<<dim3(8, 64), 256, 0, stream>>>(ob, woT, bo, nullptr, x2,
                                              cmod, 2048, x, 1024, 1024);

  // ln2 + modulate (sh_mlp @ 3072, sc_mlp @ 4096)
  ln_mod<<<8192, 256, 0, stream>>>(x2, cmod, xm2, 3072, 4096);

  // h = gelu(xm2 @ w1 + b1)
  gemm_bt<2><<<dim3(32, 64), 256, 0, stream>>>(xm2, w1T, b1, hb, nullptr,
                                               nullptr, 0, nullptr, 4096, 1024);

  // out = x2 + g_mlp * (h @ w2 + b2)    (g_mlp @ 5120)
  gemm_bt<3><<<dim3(8, 64), 256, 0, stream>>>(hb, w2T, b2, nullptr, out,
                                              cmod, 5120, x2, 1024, 4096);
}

// Round 3
// 664.842 us; speedup vs baseline: 2.3705x; 2.3705x over previous
//
#include <hip/hip_runtime.h>
#include <hip/hip_bf16.h>
#include <cstdint>

// DiT block: B=8, N=1024, HID=1024, NH=16, HD=64, MLP=4096.
// R2: all big GEMMs via bf16 MFMA 16x16x32; MFMA flash attention
// (S^T = K Q^T, O^T = V^T P^T formulation; V produced pre-transposed
// by the V-GEMM epilogue).
// R3 fix: __syncthreads() between the Ps write (softmax) and Ps read (PV)
// phases in attn_mfma — the only unfenced LDS RAW in the pipeline; the
// bf16x4-store/bf16x8-load type-pun plus no fence allowed the compiler/HW
// to break the cross-lane hand-off under replay timing.

typedef __bf16 bf16;
typedef __attribute__((ext_vector_type(8))) __bf16 bf16x8;
typedef __attribute__((ext_vector_type(4))) __bf16 bf16x4;
typedef __attribute__((ext_vector_type(4))) float f32x4;

#define SEQ   1024
#define NHID  1024
#define NHEAD 16
#define HDIM  64
#define CMS   6144          // cmod row stride

// ---------------------------------------------------------------------------
// Transpose + fp32->bf16 convert:  src [K][N] fp32  ->  dst [N][K] bf16
// ---------------------------------------------------------------------------
__global__ __launch_bounds__(256) void transpose_conv(
    const float* __restrict__ src, bf16* __restrict__ dst, int K, int N)
{
  __shared__ float tile[32][33];
  int n0 = blockIdx.x * 32, k0 = blockIdx.y * 32;
  int tx = threadIdx.x & 31, ty = threadIdx.x >> 5;   // ty in 0..7
#pragma unroll
  for (int i = 0; i < 32; i += 8)
    tile[ty + i][tx] = src[(size_t)(k0 + ty + i) * N + n0 + tx];
  __syncthreads();
#pragma unroll
  for (int i = 0; i < 32; i += 8)
    dst[(size_t)(n0 + ty + i) * K + k0 + tx] = (bf16)tile[tx][ty + i];
}

// ---------------------------------------------------------------------------
// cmod = silu(c) @ w_ada + b_ada      c:[8][1024]  w_ada:[1024][6144]
// ---------------------------------------------------------------------------
__global__ __launch_bounds__(256) void ada_kernel(
    const float* __restrict__ c, const float* __restrict__ w_ada,
    const float* __restrict__ b_ada, float* __restrict__ cmod)
{
  __shared__ float cs[1024];
  int b = blockIdx.y;
  int col = blockIdx.x * 256 + threadIdx.x;
  for (int i = threadIdx.x; i < 1024; i += 256) {
    float cv = c[b * 1024 + i];
    cs[i] = cv / (1.0f + __expf(-cv));
  }
  __syncthreads();
  float acc = b_ada[col];
#pragma unroll 8
  for (int kk = 0; kk < 1024; kk++)
    acc += cs[kk] * w_ada[(size_t)kk * CMS + col];
  cmod[b * CMS + col] = acc;
}

// ---------------------------------------------------------------------------
// LayerNorm (no affine) + modulate -> bf16.  One block per row.
// ---------------------------------------------------------------------------
__global__ __launch_bounds__(256) void ln_mod(
    const float* __restrict__ x, const float* __restrict__ cmod,
    bf16* __restrict__ out, int sh_off, int sc_off)
{
  int row = blockIdx.x, b = row >> 10, tid = threadIdx.x;
  const float4* xr = (const float4*)(x + (size_t)row * NHID);
  float4 v = xr[tid];
  float s  = v.x + v.y + v.z + v.w;
  float s2 = v.x * v.x + v.y * v.y + v.z * v.z + v.w * v.w;
#pragma unroll
  for (int off = 32; off; off >>= 1) {
    s  += __shfl_xor(s, off);
    s2 += __shfl_xor(s2, off);
  }
  __shared__ float red1[4], red2[4];
  int wave = tid >> 6, lane = tid & 63;
  if (lane == 0) { red1[wave] = s; red2[wave] = s2; }
  __syncthreads();
  float S  = red1[0] + red1[1] + red1[2] + red1[3];
  float S2 = red2[0] + red2[1] + red2[2] + red2[3];
  float mean = S * (1.0f / NHID);
  float var  = S2 * (1.0f / NHID) - mean * mean;
  float rs   = rsqrtf(var + 1e-6f);
  const float4* shp = (const float4*)(cmod + b * CMS + sh_off);
  const float4* scp = (const float4*)(cmod + b * CMS + sc_off);
  float4 sh4 = shp[tid], sc4 = scp[tid];
  bf16x4 o4;
  o4[0] = (bf16)((v.x - mean) * rs * (1.0f + sc4.x) + sh4.x);
  o4[1] = (bf16)((v.y - mean) * rs * (1.0f + sc4.y) + sh4.y);
  o4[2] = (bf16)((v.z - mean) * rs * (1.0f + sc4.z) + sh4.z);
  o4[3] = (bf16)((v.w - mean) * rs * (1.0f + sc4.w) + sh4.w);
  *(bf16x4*)(out + (size_t)row * NHID + tid * 4) = o4;
}

// ---------------------------------------------------------------------------
// GEMM: C[M][N] = A[M][K](bf16) @ Bt[N][K](bf16)^T + bias, fused epilogues.
// 128x128 tile, BK=64, 4 waves (2x2 of 64x64), mfma 16x16x32 bf16.
// EPI: 0 = bf16 out           1 = fp32 out = resid + gate*val (WO)
//      2 = bf16 gelu (W1)     3 = fp32 out = resid + gate*val (W2/final)
//      4 = bf16 TRANSPOSED out: outb[b][col][row&1023]  (V^T for attention)
// ---------------------------------------------------------------------------
template <int EPI>
__global__ __launch_bounds__(256) void gemm_bt(
    const bf16* __restrict__ A, const bf16* __restrict__ Bt,
    const float* __restrict__ bias,
    bf16* __restrict__ outb, float* __restrict__ outf,
    const float* __restrict__ cmod, int gate_off,
    const float* __restrict__ resid,
    int N, int K)
{
  __shared__ __align__(16) bf16 As[128 * 64];
  __shared__ __align__(16) bf16 Bs[128 * 64];
  const int tid = threadIdx.x;
  const int bm = blockIdx.y * 128, bn = blockIdx.x * 128;
  const int wave = tid >> 6, lane = tid & 63;
  const int quad = lane >> 4, l16 = lane & 15;
  const int wm = (wave >> 1) * 64, wn = (wave & 1) * 64;

  f32x4 acc[4][4];
#pragma unroll
  for (int i = 0; i < 4; i++)
#pragma unroll
    for (int j = 0; j < 4; j++) acc[i][j] = (f32x4)0.0f;

  for (int k0 = 0; k0 < K; k0 += 64) {
#pragma unroll
    for (int i = 0; i < 4; i++) {
      int id = tid + i * 256;          // 1024 chunks of 16B
      int r = id >> 3, cc = id & 7;
      *(uint4*)(As + r * 64 + ((cc ^ (r & 7)) * 8)) =
          *(const uint4*)(A + (size_t)(bm + r) * K + k0 + cc * 8);
      *(uint4*)(Bs + r * 64 + ((cc ^ (r & 7)) * 8)) =
          *(const uint4*)(Bt + (size_t)(bn + r) * K + k0 + cc * 8);
    }
    __syncthreads();
#pragma unroll
    for (int kk = 0; kk < 2; kk++) {
      bf16x8 af[4], bfr[4];
#pragma unroll
      for (int t = 0; t < 4; t++) {
        int ra = wm + t * 16 + l16;
        int rb = wn + t * 16 + l16;
        int cc = kk * 4 + quad;
        af[t]  = *(const bf16x8*)(As + ra * 64 + ((cc ^ (ra & 7)) * 8));
        bfr[t] = *(const bf16x8*)(Bs + rb * 64 + ((cc ^ (rb & 7)) * 8));
      }
#pragma unroll
      for (int mt = 0; mt < 4; mt++)
#pragma unroll
        for (int nt = 0; nt < 4; nt++)
          acc[mt][nt] = __builtin_amdgcn_mfma_f32_16x16x32_bf16(
              af[mt], bfr[nt], acc[mt][nt], 0, 0, 0);
    }
    __syncthreads();
  }

#pragma unroll
  for (int mt = 0; mt < 4; mt++) {
#pragma unroll
    for (int nt = 0; nt < 4; nt++) {
      int col = bn + wn + nt * 16 + l16;
      float bcol = bias[col];
      if (EPI == 4) {
        bf16x4 o4;
#pragma unroll
        for (int r = 0; r < 4; r++) o4[r] = (bf16)(acc[mt][nt][r] + bcol);
        int row0 = bm + wm + mt * 16 + quad * 4;
        int bb = row0 >> 10;
        *(bf16x4*)(outb + ((size_t)bb * NHID + col) * SEQ + (row0 & 1023)) = o4;
      } else {
#pragma unroll
        for (int r = 0; r < 4; r++) {
          int row = bm + wm + mt * 16 + quad * 4 + r;
          float val = acc[mt][nt][r] + bcol;
          if (EPI == 0) {
            outb[(size_t)row * N + col] = (bf16)val;
          } else if (EPI == 1 || EPI == 3) {
            int bb = row >> 10;
            float g = cmod[bb * CMS + gate_off + col];
            outf[(size_t)row * N + col] =
                resid[(size_t)row * N + col] + g * val;
          } else {  // EPI == 2: exact GELU
            float ge = 0.5f * val * (1.0f + erff(val * 0.70710678118f));
            outb[(size_t)row * N + col] = (bf16)ge;
          }
        }
      }
    }
  }
}

// ---------------------------------------------------------------------------
// MFMA flash attention.  Block = 256 thr (4 waves) = one (b,h) x 128 q-rows;
// wave handles 32 q-rows.  Iterates 16 K-tiles of 64 keys.
//   S^T = K @ Q^T   (A = K rows from LDS, B = Q rows from regs)
//   O^T += V^T @ P^T (A = V^T rows from LDS, B = P rows from LDS)
// C-layout of both: col = q = l16  ->  softmax reduces across quads only
// (shfl_xor 16,32); online-softmax state is per-lane aligned with O^T acc.
// v input is PRE-TRANSPOSED by the V-GEMM: vt[b][hid][seq].
// ---------------------------------------------------------------------------
__global__ __launch_bounds__(256) void attn_mfma(
    const bf16* __restrict__ q, const bf16* __restrict__ k,
    const bf16* __restrict__ vt, bf16* __restrict__ o)
{
  __shared__ __align__(16) bf16 Ks[64 * 64];
  __shared__ __align__(16) bf16 Vs[64 * 64];
  __shared__ __align__(16) bf16 Ps[4][32 * 72];   // [wave][qloc][key] stride 72

  int bid = blockIdx.x;
  int qt = bid & 7, h = (bid >> 3) & 15, b = bid >> 7;
  int tid = threadIdx.x, wave = tid >> 6, lane = tid & 63;
  int quad = lane >> 4, l16 = lane & 15;
  int qbase = qt * 128 + wave * 32;

  // Preload Q B-fragments, pre-scaled by 1/HD (exact: power of 2).
  bf16x8 qf[2][2];
  const bf16* qp = q + ((size_t)(b * SEQ + qbase)) * NHID + h * HDIM;
#pragma unroll
  for (int nt = 0; nt < 2; nt++)
#pragma unroll
    for (int kk = 0; kk < 2; kk++) {
      bf16x8 t = *(const bf16x8*)(qp + (size_t)(nt * 16 + l16) * NHID +
                                  kk * 32 + quad * 8);
#pragma unroll
      for (int j = 0; j < 8; j++) t[j] = (bf16)((float)t[j] * 0.015625f);
      qf[nt][kk] = t;
    }

  f32x4 oacc[4][2];
#pragma unroll
  for (int mt = 0; mt < 4; mt++)
#pragma unroll
    for (int nt = 0; nt < 2; nt++) oacc[mt][nt] = (f32x4)0.0f;
  float m_[2] = {-3.0e38f, -3.0e38f}, l_[2] = {0.0f, 0.0f};

  const bf16* kb = k + ((size_t)(b * SEQ)) * NHID + h * HDIM;
  const bf16* vb = vt + ((size_t)(b * NHID + h * HDIM)) * SEQ;

  for (int kt = 0; kt < 16; kt++) {
    __syncthreads();   // prior-iter K/V/P LDS reads done before restage
#pragma unroll
    for (int i = 0; i < 2; i++) {
      int id = tid + i * 256;            // 512 chunks each
      int r = id >> 3, cc = id & 7;
      *(uint4*)(Ks + r * 64 + ((cc ^ (r & 7)) * 8)) =
          *(const uint4*)(kb + (size_t)(kt * 64 + r) * NHID + cc * 8);
      *(uint4*)(Vs + r * 64 + ((cc ^ (r & 7)) * 8)) =
          *(const uint4*)(vb + (size_t)r * SEQ + kt * 64 + cc * 8);
    }
    __syncthreads();

    // ---- S^T = K @ Q^T  (already scaled via qf)
    f32x4 sacc[4][2];
#pragma unroll
    for (int mt = 0; mt < 4; mt++)
#pragma unroll
      for (int nt = 0; nt < 2; nt++) sacc[mt][nt] = (f32x4)0.0f;
#pragma unroll
    for (int kk = 0; kk < 2; kk++) {
      bf16x8 kf[4];
#pragma unroll
      for (int mt = 0; mt < 4; mt++) {
        int row = mt * 16 + l16;
        kf[mt] = *(const bf16x8*)(Ks + row * 64 +
                                  (((kk * 4 + quad) ^ (row & 7)) * 8));
      }
#pragma unroll
      for (int mt = 0; mt < 4; mt++)
#pragma unroll
        for (int nt = 0; nt < 2; nt++)
          sacc[mt][nt] = __builtin_amdgcn_mfma_f32_16x16x32_bf16(
              kf[mt], qf[nt][kk], sacc[mt][nt], 0, 0, 0);
    }

    // ---- online softmax (per q column = per (nt, l16))
    float alpha[2];
#pragma unroll
    for (int nt = 0; nt < 2; nt++) {
      float tm = -3.0e38f;
#pragma unroll
      for (int mt = 0; mt < 4; mt++)
#pragma unroll
        for (int r = 0; r < 4; r++) tm = fmaxf(tm, sacc[mt][nt][r]);
      tm = fmaxf(tm, __shfl_xor(tm, 16));
      tm = fmaxf(tm, __shfl_xor(tm, 32));
      float mn = fmaxf(m_[nt], tm);
      alpha[nt] = __expf(m_[nt] - mn);
      m_[nt] = mn;
      float ts = 0.0f;
#pragma unroll
      for (int mt = 0; mt < 4; mt++) {
        bf16x4 pv;
#pragma unroll
        for (int r = 0; r < 4; r++) {
          float p = __expf(sacc[mt][nt][r] - mn);
          ts += p;
          pv[r] = (bf16)p;
        }
        *(bf16x4*)(&Ps[wave][(nt * 16 + l16) * 72 + mt * 16 + quad * 4]) = pv;
      }
      ts += __shfl_xor(ts, 16);
      ts += __shfl_xor(ts, 32);
      l_[nt] = l_[nt] * alpha[nt] + ts;
    }
#pragma unroll
    for (int mt = 0; mt < 4; mt++)
#pragma unroll
      for (int nt = 0; nt < 2; nt++)
#pragma unroll
        for (int r = 0; r < 4; r++) oacc[mt][nt][r] *= alpha[nt];

    // R3 FIX: full barrier (compiler memory fence + HW sync) between the
    // Ps writes above and the cross-lane Ps reads below. Previously this
    // hand-off was unfenced (relying on same-wave DS ordering through a
    // bf16x4-store / bf16x8-load type-pun) -> replay-timing divergence.
    __syncthreads();

    // ---- O^T += V^T @ P^T
#pragma unroll
    for (int kk = 0; kk < 2; kk++) {
      bf16x8 vf[4], pf[2];
#pragma unroll
      for (int mt = 0; mt < 4; mt++) {
        int row = mt * 16 + l16;
        vf[mt] = *(const bf16x8*)(Vs + row * 64 +
                                  (((kk * 4 + quad) ^ (row & 7)) * 8));
      }
#pragma unroll
      for (int nt = 0; nt < 2; nt++)
        pf[nt] = *(const bf16x8*)(&Ps[wave][(nt * 16 + l16) * 72 +
                                            kk * 32 + quad * 8]);
#pragma unroll
      for (int mt = 0; mt < 4; mt++)
#pragma unroll
        for (int nt = 0; nt < 2; nt++)
          oacc[mt][nt] = __builtin_amdgcn_mfma_f32_16x16x32_bf16(
              vf[mt], pf[nt], oacc[mt][nt], 0, 0, 0);
    }
  }

  // ---- write O (un-transposing: per lane 4 consecutive hid cols)
#pragma unroll
  for (int nt = 0; nt < 2; nt++) {
    float rl = 1.0f / l_[nt];
#pragma unroll
    for (int mt = 0; mt < 4; mt++) {
      bf16x4 o4;
#pragma unroll
      for (int r = 0; r < 4; r++) o4[r] = (bf16)(oacc[mt][nt][r] * rl);
      *(bf16x4*)(o + ((size_t)(b * SEQ + qbase + nt * 16 + l16)) * NHID +
                 h * HDIM + mt * 16 + quad * 4) = o4;
    }
  }
}

// ---------------------------------------------------------------------------
// Workspace layout (bytes). Total ~136.2 MiB.
// ---------------------------------------------------------------------------
#define OFF_CMOD 0u
#define OFF_WQT  196608u
#define OFF_WKT  (OFF_WQT + 2097152u)
#define OFF_WVT  (OFF_WKT + 2097152u)
#define OFF_WOT  (OFF_WVT + 2097152u)
#define OFF_W1T  (OFF_WOT + 2097152u)
#define OFF_W2T  (OFF_W1T + 8388608u)
#define OFF_X2   (OFF_W2T + 8388608u)
#define OFF_XM2  (OFF_X2  + 33554432u)
#define OFF_POOL (OFF_XM2 + 16777216u)
// pool (67.1 MB): xm @ +0, q @ +16M, k @ +32M, vt @ +48M.
// o aliases xm (dead after QKV GEMMs); h aliases whole pool.

extern "C" void kernel_launch(void* const* d_in, const int* in_sizes, int n_in,
                              void* d_out, int out_size, void* d_ws, size_t ws_size,
                              hipStream_t stream)
{
  const float* x     = (const float*)d_in[0];
  const float* c     = (const float*)d_in[1];
  const float* w_ada = (const float*)d_in[2];
  const float* b_ada = (const float*)d_in[3];
  const float* wq = (const float*)d_in[4];  const float* bq = (const float*)d_in[5];
  const float* wk = (const float*)d_in[6];  const float* bk = (const float*)d_in[7];
  const float* wv = (const float*)d_in[8];  const float* bv = (const float*)d_in[9];
  const float* wo = (const float*)d_in[10]; const float* bo = (const float*)d_in[11];
  const float* w1 = (const float*)d_in[12]; const float* b1 = (const float*)d_in[13];
  const float* w2 = (const float*)d_in[14]; const float* b2 = (const float*)d_in[15];
  float* out = (float*)d_out;
  char* ws = (char*)d_ws;

  float* cmod = (float*)(ws + OFF_CMOD);
  bf16* wqT = (bf16*)(ws + OFF_WQT);
  bf16* wkT = (bf16*)(ws + OFF_WKT);
  bf16* wvT = (bf16*)(ws + OFF_WVT);
  bf16* woT = (bf16*)(ws + OFF_WOT);
  bf16* w1T = (bf16*)(ws + OFF_W1T);
  bf16* w2T = (bf16*)(ws + OFF_W2T);
  float* x2 = (float*)(ws + OFF_X2);
  bf16* xm2 = (bf16*)(ws + OFF_XM2);
  bf16* xm  = (bf16*)(ws + OFF_POOL);
  bf16* qb  = (bf16*)(ws + OFF_POOL + 16777216u);
  bf16* kb  = (bf16*)(ws + OFF_POOL + 33554432u);
  bf16* vtb = (bf16*)(ws + OFF_POOL + 50331648u);
  bf16* ob  = xm;   // alias
  bf16* hb  = xm;   // alias (covers 64 MB of pool)

  // weight transposes (fp32 [K][N] -> bf16 [N][K])
  transpose_conv<<<dim3(32, 32), 256, 0, stream>>>(wq, wqT, 1024, 1024);
  transpose_conv<<<dim3(32, 32), 256, 0, stream>>>(wk, wkT, 1024, 1024);
  transpose_conv<<<dim3(32, 32), 256, 0, stream>>>(wv, wvT, 1024, 1024);
  transpose_conv<<<dim3(32, 32), 256, 0, stream>>>(wo, woT, 1024, 1024);
  transpose_conv<<<dim3(128, 32), 256, 0, stream>>>(w1, w1T, 1024, 4096);
  transpose_conv<<<dim3(32, 128), 256, 0, stream>>>(w2, w2T, 4096, 1024);

  ada_kernel<<<dim3(24, 8), 256, 0, stream>>>(c, w_ada, b_ada, cmod);

  // ln1 + modulate (sh_msa @ 0, sc_msa @ 1024)
  ln_mod<<<8192, 256, 0, stream>>>(x, cmod, xm, 0, 1024);

  // QKV (V written transposed: vt[b][hid][seq])
  gemm_bt<0><<<dim3(8, 64), 256, 0, stream>>>(xm, wqT, bq, qb, nullptr,
                                              nullptr, 0, nullptr, 1024, 1024);
  gemm_bt<0><<<dim3(8, 64), 256, 0, stream>>>(xm, wkT, bk, kb, nullptr,
                                              nullptr, 0, nullptr, 1024, 1024);
  gemm_bt<4><<<dim3(8, 64), 256, 0, stream>>>(xm, wvT, bv, vtb, nullptr,
                                              nullptr, 0, nullptr, 1024, 1024);

  attn_mfma<<<1024, 256, 0, stream>>>(qb, kb, vtb, ob);

  // x2 = x + g_msa * (o @ wo + bo)      (g_msa @ 2048)
  gemm_bt<1><<<dim3(8, 64), 256, 0, stream>>>(ob, woT, bo, nullptr, x2,
                                              cmod, 2048, x, 1024, 1024);

  // ln2 + modulate (sh_mlp @ 3072, sc_mlp @ 4096)
  ln_mod<<<8192, 256, 0, stream>>>(x2, cmod, xm2, 3072, 4096);

  // h = gelu(xm2 @ w1 + b1)
  gemm_bt<2><<<dim3(32, 64), 256, 0, stream>>>(xm2, w1T, b1, hb, nullptr,
                                               nullptr, 0, nullptr, 4096, 1024);

  // out = x2 + g_mlp * (h @ w2 + b2)    (g_mlp @ 5120)
  gemm_bt<3><<<dim3(8, 64), 256, 0, stream>>>(hb, w2T, b2, nullptr, out,
                                              cmod, 5120, x2, 1024, 4096);
}

// Round 4
// 641.041 us; speedup vs baseline: 2.4585x; 1.0371x over previous
//
#include <hip/hip_runtime.h>
#include <hip/hip_bf16.h>
#include <cstdint>

// DiT block: B=8, N=1024, HID=1024, NH=16, HD=64, MLP=4096.
// R3: all big GEMMs via bf16 MFMA 16x16x32; MFMA flash attention
// (S^T = K Q^T, O^T = V^T P^T; V pre-transposed by the V-GEMM epilogue).
// R4: GEMM staging via global_load_lds width=16 (async HBM->LDS DMA, no
// VGPR round-trip). The XOR bank-swizzle is preserved by permuting the
// per-lane GLOBAL fetch address instead of the LDS store address (LDS dest
// is wave-uniform base + lane*16 and cannot scatter).

typedef __bf16 bf16;
typedef __attribute__((ext_vector_type(8))) __bf16 bf16x8;
typedef __attribute__((ext_vector_type(4))) __bf16 bf16x4;
typedef __attribute__((ext_vector_type(4))) float f32x4;

#define SEQ   1024
#define NHID  1024
#define NHEAD 16
#define HDIM  64
#define CMS   6144          // cmod row stride

// async 16B global->LDS: lds dest = wave-uniform base + lane*16
#define GLD16(gp, lp)                                                  \
  __builtin_amdgcn_global_load_lds(                                    \
      (const __attribute__((address_space(1))) void*)(gp),             \
      (__attribute__((address_space(3))) void*)(lp), 16, 0, 0)

// ---------------------------------------------------------------------------
// Transpose + fp32->bf16 convert:  src [K][N] fp32  ->  dst [N][K] bf16
// ---------------------------------------------------------------------------
__global__ __launch_bounds__(256) void transpose_conv(
    const float* __restrict__ src, bf16* __restrict__ dst, int K, int N)
{
  __shared__ float tile[32][33];
  int n0 = blockIdx.x * 32, k0 = blockIdx.y * 32;
  int tx = threadIdx.x & 31, ty = threadIdx.x >> 5;   // ty in 0..7
#pragma unroll
  for (int i = 0; i < 32; i += 8)
    tile[ty + i][tx] = src[(size_t)(k0 + ty + i) * N + n0 + tx];
  __syncthreads();
#pragma unroll
  for (int i = 0; i < 32; i += 8)
    dst[(size_t)(n0 + ty + i) * K + k0 + tx] = (bf16)tile[tx][ty + i];
}

// ---------------------------------------------------------------------------
// cmod = silu(c) @ w_ada + b_ada      c:[8][1024]  w_ada:[1024][6144]
// ---------------------------------------------------------------------------
__global__ __launch_bounds__(256) void ada_kernel(
    const float* __restrict__ c, const float* __restrict__ w_ada,
    const float* __restrict__ b_ada, float* __restrict__ cmod)
{
  __shared__ float cs[1024];
  int b = blockIdx.y;
  int col = blockIdx.x * 256 + threadIdx.x;
  for (int i = threadIdx.x; i < 1024; i += 256) {
    float cv = c[b * 1024 + i];
    cs[i] = cv / (1.0f + __expf(-cv));
  }
  __syncthreads();
  float acc = b_ada[col];
#pragma unroll 8
  for (int kk = 0; kk < 1024; kk++)
    acc += cs[kk] * w_ada[(size_t)kk * CMS + col];
  cmod[b * CMS + col] = acc;
}

// ---------------------------------------------------------------------------
// LayerNorm (no affine) + modulate -> bf16.  One block per row.
// ---------------------------------------------------------------------------
__global__ __launch_bounds__(256) void ln_mod(
    const float* __restrict__ x, const float* __restrict__ cmod,
    bf16* __restrict__ out, int sh_off, int sc_off)
{
  int row = blockIdx.x, b = row >> 10, tid = threadIdx.x;
  const float4* xr = (const float4*)(x + (size_t)row * NHID);
  float4 v = xr[tid];
  float s  = v.x + v.y + v.z + v.w;
  float s2 = v.x * v.x + v.y * v.y + v.z * v.z + v.w * v.w;
#pragma unroll
  for (int off = 32; off; off >>= 1) {
    s  += __shfl_xor(s, off);
    s2 += __shfl_xor(s2, off);
  }
  __shared__ float red1[4], red2[4];
  int wave = tid >> 6, lane = tid & 63;
  if (lane == 0) { red1[wave] = s; red2[wave] = s2; }
  __syncthreads();
  float S  = red1[0] + red1[1] + red1[2] + red1[3];
  float S2 = red2[0] + red2[1] + red2[2] + red2[3];
  float mean = S * (1.0f / NHID);
  float var  = S2 * (1.0f / NHID) - mean * mean;
  float rs   = rsqrtf(var + 1e-6f);
  const float4* shp = (const float4*)(cmod + b * CMS + sh_off);
  const float4* scp = (const float4*)(cmod + b * CMS + sc_off);
  float4 sh4 = shp[tid], sc4 = scp[tid];
  bf16x4 o4;
  o4[0] = (bf16)((v.x - mean) * rs * (1.0f + sc4.x) + sh4.x);
  o4[1] = (bf16)((v.y - mean) * rs * (1.0f + sc4.y) + sh4.y);
  o4[2] = (bf16)((v.z - mean) * rs * (1.0f + sc4.z) + sh4.z);
  o4[3] = (bf16)((v.w - mean) * rs * (1.0f + sc4.w) + sh4.w);
  *(bf16x4*)(out + (size_t)row * NHID + tid * 4) = o4;
}

// ---------------------------------------------------------------------------
// GEMM: C[M][N] = A[M][K](bf16) @ Bt[N][K](bf16)^T + bias, fused epilogues.
// 128x128 tile, BK=64, 4 waves (2x2 of 64x64), mfma 16x16x32 bf16.
// Staging: global_load_lds width=16; swizzle folded into the global fetch
// address (LDS image identical to R3's, so fragment reads are conflict-free).
// EPI: 0 = bf16 out           1 = fp32 out = resid + gate*val (WO)
//      2 = bf16 gelu (W1)     3 = fp32 out = resid + gate*val (W2/final)
//      4 = bf16 TRANSPOSED out: outb[b][col][row&1023]  (V^T for attention)
// ---------------------------------------------------------------------------
template <int EPI>
__global__ __launch_bounds__(256) void gemm_bt(
    const bf16* __restrict__ A, const bf16* __restrict__ Bt,
    const float* __restrict__ bias,
    bf16* __restrict__ outb, float* __restrict__ outf,
    const float* __restrict__ cmod, int gate_off,
    const float* __restrict__ resid,
    int N, int K)
{
  __shared__ __align__(16) bf16 As[128 * 64];
  __shared__ __align__(16) bf16 Bs[128 * 64];
  const int tid = threadIdx.x;
  const int bm = blockIdx.y * 128, bn = blockIdx.x * 128;
  const int wave = tid >> 6, lane = tid & 63;
  const int quad = lane >> 4, l16 = lane & 15;
  const int wm = (wave >> 1) * 64, wn = (wave & 1) * 64;

  // staging address precompute: chunk idx = i*256 + tid; LDS pos (r,c)
  // receives global chunk (r, c^(r&7)).
  const int sr = tid >> 3;                 // row for i=0 (r = i*32 + sr)
  const int sc = tid & 7;

  f32x4 acc[4][4];
#pragma unroll
  for (int i = 0; i < 4; i++)
#pragma unroll
    for (int j = 0; j < 4; j++) acc[i][j] = (f32x4)0.0f;

  for (int k0 = 0; k0 < K; k0 += 64) {
#pragma unroll
    for (int i = 0; i < 4; i++) {
      int r = i * 32 + sr;
      int cg = (sc ^ (r & 7)) * 8;
      bf16* lbase_a = As + (size_t)(i * 256 + (tid & 192)) * 8;
      bf16* lbase_b = Bs + (size_t)(i * 256 + (tid & 192)) * 8;
      GLD16(A  + (size_t)(bm + r) * K + k0 + cg, lbase_a);
      GLD16(Bt + (size_t)(bn + r) * K + k0 + cg, lbase_b);
    }
    __syncthreads();
#pragma unroll
    for (int kk = 0; kk < 2; kk++) {
      bf16x8 af[4], bfr[4];
#pragma unroll
      for (int t = 0; t < 4; t++) {
        int ra = wm + t * 16 + l16;
        int rb = wn + t * 16 + l16;
        int cc = kk * 4 + quad;
        af[t]  = *(const bf16x8*)(As + ra * 64 + ((cc ^ (ra & 7)) * 8));
        bfr[t] = *(const bf16x8*)(Bs + rb * 64 + ((cc ^ (rb & 7)) * 8));
      }
#pragma unroll
      for (int mt = 0; mt < 4; mt++)
#pragma unroll
        for (int nt = 0; nt < 4; nt++)
          acc[mt][nt] = __builtin_amdgcn_mfma_f32_16x16x32_bf16(
              af[mt], bfr[nt], acc[mt][nt], 0, 0, 0);
    }
    __syncthreads();
  }

#pragma unroll
  for (int mt = 0; mt < 4; mt++) {
#pragma unroll
    for (int nt = 0; nt < 4; nt++) {
      int col = bn + wn + nt * 16 + l16;
      float bcol = bias[col];
      if (EPI == 4) {
        bf16x4 o4;
#pragma unroll
        for (int r = 0; r < 4; r++) o4[r] = (bf16)(acc[mt][nt][r] + bcol);
        int row0 = bm + wm + mt * 16 + quad * 4;
        int bb = row0 >> 10;
        *(bf16x4*)(outb + ((size_t)bb * NHID + col) * SEQ + (row0 & 1023)) = o4;
      } else {
#pragma unroll
        for (int r = 0; r < 4; r++) {
          int row = bm + wm + mt * 16 + quad * 4 + r;
          float val = acc[mt][nt][r] + bcol;
          if (EPI == 0) {
            outb[(size_t)row * N + col] = (bf16)val;
          } else if (EPI == 1 || EPI == 3) {
            int bb = row >> 10;
            float g = cmod[bb * CMS + gate_off + col];
            outf[(size_t)row * N + col] =
                resid[(size_t)row * N + col] + g * val;
          } else {  // EPI == 2: exact GELU
            float ge = 0.5f * val * (1.0f + erff(val * 0.70710678118f));
            outb[(size_t)row * N + col] = (bf16)ge;
          }
        }
      }
    }
  }
}

// ---------------------------------------------------------------------------
// MFMA flash attention.  Block = 256 thr (4 waves) = one (b,h) x 128 q-rows;
// wave handles 32 q-rows.  Iterates 16 K-tiles of 64 keys.
//   S^T = K @ Q^T   (A = K rows from LDS, B = Q rows from regs)
//   O^T += V^T @ P^T (A = V^T rows from LDS, B = P rows from LDS)
// C-layout of both: col = q = l16  ->  softmax reduces across quads only
// (shfl_xor 16,32); online-softmax state is per-lane aligned with O^T acc.
// v input is PRE-TRANSPOSED by the V-GEMM: vt[b][hid][seq].
// ---------------------------------------------------------------------------
__global__ __launch_bounds__(256) void attn_mfma(
    const bf16* __restrict__ q, const bf16* __restrict__ k,
    const bf16* __restrict__ vt, bf16* __restrict__ o)
{
  __shared__ __align__(16) bf16 Ks[64 * 64];
  __shared__ __align__(16) bf16 Vs[64 * 64];
  __shared__ __align__(16) bf16 Ps[4][32 * 72];   // [wave][qloc][key] stride 72

  int bid = blockIdx.x;
  int qt = bid & 7, h = (bid >> 3) & 15, b = bid >> 7;
  int tid = threadIdx.x, wave = tid >> 6, lane = tid & 63;
  int quad = lane >> 4, l16 = lane & 15;
  int qbase = qt * 128 + wave * 32;

  // Preload Q B-fragments, pre-scaled by 1/HD (exact: power of 2).
  bf16x8 qf[2][2];
  const bf16* qp = q + ((size_t)(b * SEQ + qbase)) * NHID + h * HDIM;
#pragma unroll
  for (int nt = 0; nt < 2; nt++)
#pragma unroll
    for (int kk = 0; kk < 2; kk++) {
      bf16x8 t = *(const bf16x8*)(qp + (size_t)(nt * 16 + l16) * NHID +
                                  kk * 32 + quad * 8);
#pragma unroll
      for (int j = 0; j < 8; j++) t[j] = (bf16)((float)t[j] * 0.015625f);
      qf[nt][kk] = t;
    }

  f32x4 oacc[4][2];
#pragma unroll
  for (int mt = 0; mt < 4; mt++)
#pragma unroll
    for (int nt = 0; nt < 2; nt++) oacc[mt][nt] = (f32x4)0.0f;
  float m_[2] = {-3.0e38f, -3.0e38f}, l_[2] = {0.0f, 0.0f};

  const bf16* kb = k + ((size_t)(b * SEQ)) * NHID + h * HDIM;
  const bf16* vb = vt + ((size_t)(b * NHID + h * HDIM)) * SEQ;

  for (int kt = 0; kt < 16; kt++) {
    __syncthreads();   // prior-iter K/V/P LDS reads done before restage
#pragma unroll
    for (int i = 0; i < 2; i++) {
      int id = tid + i * 256;            // 512 chunks each
      int r = id >> 3, cc = id & 7;
      *(uint4*)(Ks + r * 64 + ((cc ^ (r & 7)) * 8)) =
          *(const uint4*)(kb + (size_t)(kt * 64 + r) * NHID + cc * 8);
      *(uint4*)(Vs + r * 64 + ((cc ^ (r & 7)) * 8)) =
          *(const uint4*)(vb + (size_t)r * SEQ + kt * 64 + cc * 8);
    }
    __syncthreads();

    // ---- S^T = K @ Q^T  (already scaled via qf)
    f32x4 sacc[4][2];
#pragma unroll
    for (int mt = 0; mt < 4; mt++)
#pragma unroll
      for (int nt = 0; nt < 2; nt++) sacc[mt][nt] = (f32x4)0.0f;
#pragma unroll
    for (int kk = 0; kk < 2; kk++) {
      bf16x8 kf[4];
#pragma unroll
      for (int mt = 0; mt < 4; mt++) {
        int row = mt * 16 + l16;
        kf[mt] = *(const bf16x8*)(Ks + row * 64 +
                                  (((kk * 4 + quad) ^ (row & 7)) * 8));
      }
#pragma unroll
      for (int mt = 0; mt < 4; mt++)
#pragma unroll
        for (int nt = 0; nt < 2; nt++)
          sacc[mt][nt] = __builtin_amdgcn_mfma_f32_16x16x32_bf16(
              kf[mt], qf[nt][kk], sacc[mt][nt], 0, 0, 0);
    }

    // ---- online softmax (per q column = per (nt, l16))
    float alpha[2];
#pragma unroll
    for (int nt = 0; nt < 2; nt++) {
      float tm = -3.0e38f;
#pragma unroll
      for (int mt = 0; mt < 4; mt++)
#pragma unroll
        for (int r = 0; r < 4; r++) tm = fmaxf(tm, sacc[mt][nt][r]);
      tm = fmaxf(tm, __shfl_xor(tm, 16));
      tm = fmaxf(tm, __shfl_xor(tm, 32));
      float mn = fmaxf(m_[nt], tm);
      alpha[nt] = __expf(m_[nt] - mn);
      m_[nt] = mn;
      float ts = 0.0f;
#pragma unroll
      for (int mt = 0; mt < 4; mt++) {
        bf16x4 pv;
#pragma unroll
        for (int r = 0; r < 4; r++) {
          float p = __expf(sacc[mt][nt][r] - mn);
          ts += p;
          pv[r] = (bf16)p;
        }
        *(bf16x4*)(&Ps[wave][(nt * 16 + l16) * 72 + mt * 16 + quad * 4]) = pv;
      }
      ts += __shfl_xor(ts, 16);
      ts += __shfl_xor(ts, 32);
      l_[nt] = l_[nt] * alpha[nt] + ts;
    }
#pragma unroll
    for (int mt = 0; mt < 4; mt++)
#pragma unroll
      for (int nt = 0; nt < 2; nt++)
#pragma unroll
        for (int r = 0; r < 4; r++) oacc[mt][nt][r] *= alpha[nt];

    // Full barrier between the Ps writes (softmax) and cross-lane Ps reads
    // (PV) — this hand-off must be fenced (R3 post-mortem).
    __syncthreads();

    // ---- O^T += V^T @ P^T
#pragma unroll
    for (int kk = 0; kk < 2; kk++) {
      bf16x8 vf[4], pf[2];
#pragma unroll
      for (int mt = 0; mt < 4; mt++) {
        int row = mt * 16 + l16;
        vf[mt] = *(const bf16x8*)(Vs + row * 64 +
                                  (((kk * 4 + quad) ^ (row & 7)) * 8));
      }
#pragma unroll
      for (int nt = 0; nt < 2; nt++)
        pf[nt] = *(const bf16x8*)(&Ps[wave][(nt * 16 + l16) * 72 +
                                            kk * 32 + quad * 8]);
#pragma unroll
      for (int mt = 0; mt < 4; mt++)
#pragma unroll
        for (int nt = 0; nt < 2; nt++)
          oacc[mt][nt] = __builtin_amdgcn_mfma_f32_16x16x32_bf16(
              vf[mt], pf[nt], oacc[mt][nt], 0, 0, 0);
    }
  }

  // ---- write O (un-transposing: per lane 4 consecutive hid cols)
#pragma unroll
  for (int nt = 0; nt < 2; nt++) {
    float rl = 1.0f / l_[nt];
#pragma unroll
    for (int mt = 0; mt < 4; mt++) {
      bf16x4 o4;
#pragma unroll
      for (int r = 0; r < 4; r++) o4[r] = (bf16)(oacc[mt][nt][r] * rl);
      *(bf16x4*)(o + ((size_t)(b * SEQ + qbase + nt * 16 + l16)) * NHID +
                 h * HDIM + mt * 16 + quad * 4) = o4;
    }
  }
}

// ---------------------------------------------------------------------------
// Workspace layout (bytes). Total ~136.2 MiB.
// ---------------------------------------------------------------------------
#define OFF_CMOD 0u
#define OFF_WQT  196608u
#define OFF_WKT  (OFF_WQT + 2097152u)
#define OFF_WVT  (OFF_WKT + 2097152u)
#define OFF_WOT  (OFF_WVT + 2097152u)
#define OFF_W1T  (OFF_WOT + 2097152u)
#define OFF_W2T  (OFF_W1T + 8388608u)
#define OFF_X2   (OFF_W2T + 8388608u)
#define OFF_XM2  (OFF_X2  + 33554432u)
#define OFF_POOL (OFF_XM2 + 16777216u)
// pool (67.1 MB): xm @ +0, q @ +16M, k @ +32M, vt @ +48M.
// o aliases xm (dead after QKV GEMMs); h aliases whole pool.

extern "C" void kernel_launch(void* const* d_in, const int* in_sizes, int n_in,
                              void* d_out, int out_size, void* d_ws, size_t ws_size,
                              hipStream_t stream)
{
  const float* x     = (const float*)d_in[0];
  const float* c     = (const float*)d_in[1];
  const float* w_ada = (const float*)d_in[2];
  const float* b_ada = (const float*)d_in[3];
  const float* wq = (const float*)d_in[4];  const float* bq = (const float*)d_in[5];
  const float* wk = (const float*)d_in[6];  const float* bk = (const float*)d_in[7];
  const float* wv = (const float*)d_in[8];  const float* bv = (const float*)d_in[9];
  const float* wo = (const float*)d_in[10]; const float* bo = (const float*)d_in[11];
  const float* w1 = (const float*)d_in[12]; const float* b1 = (const float*)d_in[13];
  const float* w2 = (const float*)d_in[14]; const float* b2 = (const float*)d_in[15];
  float* out = (float*)d_out;
  char* ws = (char*)d_ws;

  float* cmod = (float*)(ws + OFF_CMOD);
  bf16* wqT = (bf16*)(ws + OFF_WQT);
  bf16* wkT = (bf16*)(ws + OFF_WKT);
  bf16* wvT = (bf16*)(ws + OFF_WVT);
  bf16* woT = (bf16*)(ws + OFF_WOT);
  bf16* w1T = (bf16*)(ws + OFF_W1T);
  bf16* w2T = (bf16*)(ws + OFF_W2T);
  float* x2 = (float*)(ws + OFF_X2);
  bf16* xm2 = (bf16*)(ws + OFF_XM2);
  bf16* xm  = (bf16*)(ws + OFF_POOL);
  bf16* qb  = (bf16*)(ws + OFF_POOL + 16777216u);
  bf16* kb  = (bf16*)(ws + OFF_POOL + 33554432u);
  bf16* vtb = (bf16*)(ws + OFF_POOL + 50331648u);
  bf16* ob  = xm;   // alias
  bf16* hb  = xm;   // alias (covers 64 MB of pool)

  // weight transposes (fp32 [K][N] -> bf16 [N][K])
  transpose_conv<<<dim3(32, 32), 256, 0, stream>>>(wq, wqT, 1024, 1024);
  transpose_conv<<<dim3(32, 32), 256, 0, stream>>>(wk, wkT, 1024, 1024);
  transpose_conv<<<dim3(32, 32), 256, 0, stream>>>(wv, wvT, 1024, 1024);
  transpose_conv<<<dim3(32, 32), 256, 0, stream>>>(wo, woT, 1024, 1024);
  transpose_conv<<<dim3(128, 32), 256, 0, stream>>>(w1, w1T, 1024, 4096);
  transpose_conv<<<dim3(32, 128), 256, 0, stream>>>(w2, w2T, 4096, 1024);

  ada_kernel<<<dim3(24, 8), 256, 0, stream>>>(c, w_ada, b_ada, cmod);

  // ln1 + modulate (sh_msa @ 0, sc_msa @ 1024)
  ln_mod<<<8192, 256, 0, stream>>>(x, cmod, xm, 0, 1024);

  // QKV (V written transposed: vt[b][hid][seq])
  gemm_bt<0><<<dim3(8, 64), 256, 0, stream>>>(xm, wqT, bq, qb, nullptr,
                                              nullptr, 0, nullptr, 1024, 1024);
  gemm_bt<0><<<dim3(8, 64), 256, 0, stream>>>(xm, wkT, bk, kb, nullptr,
                                              nullptr, 0, nullptr, 1024, 1024);
  gemm_bt<4><<<dim3(8, 64), 256, 0, stream>>>(xm, wvT, bv, vtb, nullptr,
                                              nullptr, 0, nullptr, 1024, 1024);

  attn_mfma<<<1024, 256, 0, stream>>>(qb, kb, vtb, ob);

  // x2 = x + g_msa * (o @ wo + bo)      (g_msa @ 2048)
  gemm_bt<1><<<dim3(8, 64), 256, 0, stream>>>(ob, woT, bo, nullptr, x2,
                                              cmod, 2048, x, 1024, 1024);

  // ln2 + modulate (sh_mlp @ 3072, sc_mlp @ 4096)
  ln_mod<<<8192, 256, 0, stream>>>(x2, cmod, xm2, 3072, 4096);

  // h = gelu(xm2 @ w1 + b1)
  gemm_bt<2><<<dim3(32, 64), 256, 0, stream>>>(xm2, w1T, b1, hb, nullptr,
                                               nullptr, 0, nullptr, 4096, 1024);

  // out = x2 + g_mlp * (h @ w2 + b2)    (g_mlp @ 5120)
  gemm_bt<3><<<dim3(8, 64), 256, 0, stream>>>(hb, w2T, b2, nullptr, out,
                                              cmod, 5120, x2, 1024, 4096);
}

// Round 5
// 593.382 us; speedup vs baseline: 2.6559x; 1.0803x over previous
//
#include <hip/hip_runtime.h>
#include <hip/hip_bf16.h>
#include <cstdint>

// DiT block: B=8, N=1024, HID=1024, NH=16, HD=64, MLP=4096.
// R5: fused QKV GEMM (N=3072, per-block epilogue select, V transposed),
// XCD-aware block swizzle in gemm_bt (L2 panel locality), tanh-form GELU
// (branch-free, no erff), attention staged via global_load_lds with the
// mid-iteration block barrier replaced by a wave-level lgkmcnt fence
// (Ps is wave-private; asm memory clobber pins compiler ordering).

typedef __bf16 bf16;
typedef __attribute__((ext_vector_type(8))) __bf16 bf16x8;
typedef __attribute__((ext_vector_type(4))) __bf16 bf16x4;
typedef __attribute__((ext_vector_type(4))) float f32x4;

#define SEQ   1024
#define NHID  1024
#define NHEAD 16
#define HDIM  64
#define CMS   6144          // cmod row stride

// async 16B global->LDS: lds dest = wave-uniform base + lane*16
#define GLD16(gp, lp)                                                  \
  __builtin_amdgcn_global_load_lds(                                    \
      (const __attribute__((address_space(1))) void*)(gp),             \
      (__attribute__((address_space(3))) void*)(lp), 16, 0, 0)

// ---------------------------------------------------------------------------
// Batched transpose + fp32->bf16 convert for four 1024x1024 weights.
// src [K][N] fp32 -> dst [N][K] bf16;  z selects the weight.
// ---------------------------------------------------------------------------
struct TP4 { const float* s[4]; bf16* d[4]; };

__global__ __launch_bounds__(256) void transpose_conv4(TP4 p)
{
  __shared__ float tile[32][33];
  const float* __restrict__ src = p.s[blockIdx.z];
  bf16* __restrict__ dst = p.d[blockIdx.z];
  int n0 = blockIdx.x * 32, k0 = blockIdx.y * 32;
  int tx = threadIdx.x & 31, ty = threadIdx.x >> 5;
#pragma unroll
  for (int i = 0; i < 32; i += 8)
    tile[ty + i][tx] = src[(size_t)(k0 + ty + i) * 1024 + n0 + tx];
  __syncthreads();
#pragma unroll
  for (int i = 0; i < 32; i += 8)
    dst[(size_t)(n0 + ty + i) * 1024 + k0 + tx] = (bf16)tile[tx][ty + i];
}

// single transpose for the MLP weights
__global__ __launch_bounds__(256) void transpose_conv(
    const float* __restrict__ src, bf16* __restrict__ dst, int K, int N)
{
  __shared__ float tile[32][33];
  int n0 = blockIdx.x * 32, k0 = blockIdx.y * 32;
  int tx = threadIdx.x & 31, ty = threadIdx.x >> 5;
#pragma unroll
  for (int i = 0; i < 32; i += 8)
    tile[ty + i][tx] = src[(size_t)(k0 + ty + i) * N + n0 + tx];
  __syncthreads();
#pragma unroll
  for (int i = 0; i < 32; i += 8)
    dst[(size_t)(n0 + ty + i) * K + k0 + tx] = (bf16)tile[tx][ty + i];
}

// ---------------------------------------------------------------------------
// cmod = silu(c) @ w_ada + b_ada      c:[8][1024]  w_ada:[1024][6144]
// ---------------------------------------------------------------------------
__global__ __launch_bounds__(256) void ada_kernel(
    const float* __restrict__ c, const float* __restrict__ w_ada,
    const float* __restrict__ b_ada, float* __restrict__ cmod)
{
  __shared__ float cs[1024];
  int b = blockIdx.y;
  int col = blockIdx.x * 256 + threadIdx.x;
  for (int i = threadIdx.x; i < 1024; i += 256) {
    float cv = c[b * 1024 + i];
    cs[i] = cv / (1.0f + __expf(-cv));
  }
  __syncthreads();
  float acc = b_ada[col];
#pragma unroll 8
  for (int kk = 0; kk < 1024; kk++)
    acc += cs[kk] * w_ada[(size_t)kk * CMS + col];
  cmod[b * CMS + col] = acc;
}

// ---------------------------------------------------------------------------
// LayerNorm (no affine) + modulate -> bf16.  One block per row.
// ---------------------------------------------------------------------------
__global__ __launch_bounds__(256) void ln_mod(
    const float* __restrict__ x, const float* __restrict__ cmod,
    bf16* __restrict__ out, int sh_off, int sc_off)
{
  int row = blockIdx.x, b = row >> 10, tid = threadIdx.x;
  const float4* xr = (const float4*)(x + (size_t)row * NHID);
  float4 v = xr[tid];
  float s  = v.x + v.y + v.z + v.w;
  float s2 = v.x * v.x + v.y * v.y + v.z * v.z + v.w * v.w;
#pragma unroll
  for (int off = 32; off; off >>= 1) {
    s  += __shfl_xor(s, off);
    s2 += __shfl_xor(s2, off);
  }
  __shared__ float red1[4], red2[4];
  int wave = tid >> 6, lane = tid & 63;
  if (lane == 0) { red1[wave] = s; red2[wave] = s2; }
  __syncthreads();
  float S  = red1[0] + red1[1] + red1[2] + red1[3];
  float S2 = red2[0] + red2[1] + red2[2] + red2[3];
  float mean = S * (1.0f / NHID);
  float var  = S2 * (1.0f / NHID) - mean * mean;
  float rs   = rsqrtf(var + 1e-6f);
  const float4* shp = (const float4*)(cmod + b * CMS + sh_off);
  const float4* scp = (const float4*)(cmod + b * CMS + sc_off);
  float4 sh4 = shp[tid], sc4 = scp[tid];
  bf16x4 o4;
  o4[0] = (bf16)((v.x - mean) * rs * (1.0f + sc4.x) + sh4.x);
  o4[1] = (bf16)((v.y - mean) * rs * (1.0f + sc4.y) + sh4.y);
  o4[2] = (bf16)((v.z - mean) * rs * (1.0f + sc4.z) + sh4.z);
  o4[3] = (bf16)((v.w - mean) * rs * (1.0f + sc4.w) + sh4.w);
  *(bf16x4*)(out + (size_t)row * NHID + tid * 4) = o4;
}

// ---------------------------------------------------------------------------
// GEMM: C[M][N] = A[M][K](bf16) @ Bt[N][K](bf16)^T + bias, fused epilogues.
// 128x128 tile, BK=64, 4 waves (2x2 of 64x64), mfma 16x16x32 bf16.
// Staging: global_load_lds width=16; swizzle folded into global fetch addr.
// Block index XCD-swizzled: all column-blocks of one row-panel land on one
// XCD so the A-panel stays in that XCD's L2 (requires gridDim.y % 8 == 0).
// EPI: 1 = fp32 out = resid + gate*val (WO)
//      2 = bf16 tanh-gelu (W1)   3 = fp32 out = resid + gate*val (W2/final)
//      5 = fused QKV: col<1024 -> q, <2048 -> k, else v TRANSPOSED
// ---------------------------------------------------------------------------
template <int EPI>
__global__ __launch_bounds__(256) void gemm_bt(
    const bf16* __restrict__ A, const bf16* __restrict__ Bt,
    const float* __restrict__ bias, const float* __restrict__ bias2,
    const float* __restrict__ bias3,
    bf16* __restrict__ outb, bf16* __restrict__ outb2,
    bf16* __restrict__ outb3, float* __restrict__ outf,
    const float* __restrict__ cmod, int gate_off,
    const float* __restrict__ resid,
    int N, int K)
{
  __shared__ __align__(16) bf16 As[128 * 64];
  __shared__ __align__(16) bf16 Bs[128 * 64];
  const int tid = threadIdx.x;

  // XCD swizzle: lid -> (xcd, slot); same by-panel stays on one XCD.
  const int gx = gridDim.x;
  const int lid = blockIdx.y * gx + blockIdx.x;
  const int xcd = lid & 7, slot = lid >> 3;
  const int P = gridDim.y >> 3;            // by-panels per XCD
  const int by = xcd * P + slot / gx;
  const int bx = slot % gx;
  const int bm = by * 128, bn = bx * 128;

  const int wave = tid >> 6, lane = tid & 63;
  const int quad = lane >> 4, l16 = lane & 15;
  const int wm = (wave >> 1) * 64, wn = (wave & 1) * 64;

  const int sr = tid >> 3;                 // staging row for i=0
  const int sc = tid & 7;

  f32x4 acc[4][4];
#pragma unroll
  for (int i = 0; i < 4; i++)
#pragma unroll
    for (int j = 0; j < 4; j++) acc[i][j] = (f32x4)0.0f;

  for (int k0 = 0; k0 < K; k0 += 64) {
#pragma unroll
    for (int i = 0; i < 4; i++) {
      int r = i * 32 + sr;
      int cg = (sc ^ (r & 7)) * 8;
      bf16* lbase_a = As + (size_t)(i * 256 + (tid & 192)) * 8;
      bf16* lbase_b = Bs + (size_t)(i * 256 + (tid & 192)) * 8;
      GLD16(A  + (size_t)(bm + r) * K + k0 + cg, lbase_a);
      GLD16(Bt + (size_t)(bn + r) * K + k0 + cg, lbase_b);
    }
    __syncthreads();
#pragma unroll
    for (int kk = 0; kk < 2; kk++) {
      bf16x8 af[4], bfr[4];
#pragma unroll
      for (int t = 0; t < 4; t++) {
        int ra = wm + t * 16 + l16;
        int rb = wn + t * 16 + l16;
        int cc = kk * 4 + quad;
        af[t]  = *(const bf16x8*)(As + ra * 64 + ((cc ^ (ra & 7)) * 8));
        bfr[t] = *(const bf16x8*)(Bs + rb * 64 + ((cc ^ (rb & 7)) * 8));
      }
#pragma unroll
      for (int mt = 0; mt < 4; mt++)
#pragma unroll
        for (int nt = 0; nt < 4; nt++)
          acc[mt][nt] = __builtin_amdgcn_mfma_f32_16x16x32_bf16(
              af[mt], bfr[nt], acc[mt][nt], 0, 0, 0);
    }
    __syncthreads();
  }

  // block-uniform epilogue select for EPI==5
  const int sel = bn >> 10;
  const float* bp = (EPI == 5)
      ? ((sel == 0) ? bias : (sel == 1) ? bias2 : bias3) : bias;
  bf16* qk_out = (EPI == 5) ? ((sel == 0) ? outb : outb2) : outb;

#pragma unroll
  for (int mt = 0; mt < 4; mt++) {
#pragma unroll
    for (int nt = 0; nt < 4; nt++) {
      int col = bn + wn + nt * 16 + l16;
      int colq = col & 1023;
      float bcol = (EPI == 5) ? bp[colq] : bias[col];
      if (EPI == 5 && sel == 2) {
        // V: transposed write vt[b][hid][seq]
        bf16x4 o4;
#pragma unroll
        for (int r = 0; r < 4; r++) o4[r] = (bf16)(acc[mt][nt][r] + bcol);
        int row0 = bm + wm + mt * 16 + quad * 4;
        int bb = row0 >> 10;
        *(bf16x4*)(outb3 + ((size_t)bb * NHID + colq) * SEQ + (row0 & 1023)) = o4;
      } else if (EPI == 5) {
#pragma unroll
        for (int r = 0; r < 4; r++) {
          int row = bm + wm + mt * 16 + quad * 4 + r;
          qk_out[(size_t)row * 1024 + colq] = (bf16)(acc[mt][nt][r] + bcol);
        }
      } else {
#pragma unroll
        for (int r = 0; r < 4; r++) {
          int row = bm + wm + mt * 16 + quad * 4 + r;
          float val = acc[mt][nt][r] + bcol;
          if (EPI == 1 || EPI == 3) {
            int bb = row >> 10;
            float g = cmod[bb * CMS + gate_off + col];
            outf[(size_t)row * N + col] =
                resid[(size_t)row * N + col] + g * val;
          } else {  // EPI == 2: tanh-form GELU (branch-free, ~3e-3 abs dev)
            float u2 = 2.0f * val * (0.7978845608f +
                                     0.0356774081f * val * val);
            float e = __expf(u2);
            float th = 1.0f - 2.0f / (e + 1.0f);
            outb[(size_t)row * N + col] = (bf16)(0.5f * val * (1.0f + th));
          }
        }
      }
    }
  }
}

// ---------------------------------------------------------------------------
// MFMA flash attention.  Block = 256 thr (4 waves) = one (b,h) x 128 q-rows;
// wave handles 32 q-rows.  Iterates 16 K-tiles of 64 keys.
//   S^T = K @ Q^T   (A = K rows from LDS, B = Q rows from regs)
//   O^T += V^T @ P^T (A = V^T rows from LDS, B = P rows from LDS)
// K/V staged via global_load_lds (swizzle folded into global address).
// Ps hand-off is wave-private: wave-level lgkmcnt fence (asm memory clobber
// pins compiler ordering; waits for this wave's DS writes to complete).
// ---------------------------------------------------------------------------
__global__ __launch_bounds__(256) void attn_mfma(
    const bf16* __restrict__ q, const bf16* __restrict__ k,
    const bf16* __restrict__ vt, bf16* __restrict__ o)
{
  __shared__ __align__(16) bf16 Ks[64 * 64];
  __shared__ __align__(16) bf16 Vs[64 * 64];
  __shared__ __align__(16) bf16 Ps[4][32 * 72];   // [wave][qloc][key] stride 72

  int bid = blockIdx.x;
  int qt = bid & 7, h = (bid >> 3) & 15, b = bid >> 7;
  int tid = threadIdx.x, wave = tid >> 6, lane = tid & 63;
  int quad = lane >> 4, l16 = lane & 15;
  int qbase = qt * 128 + wave * 32;

  // Preload Q B-fragments, pre-scaled by 1/HD (exact: power of 2).
  bf16x8 qf[2][2];
  const bf16* qp = q + ((size_t)(b * SEQ + qbase)) * NHID + h * HDIM;
#pragma unroll
  for (int nt = 0; nt < 2; nt++)
#pragma unroll
    for (int kk = 0; kk < 2; kk++) {
      bf16x8 t = *(const bf16x8*)(qp + (size_t)(nt * 16 + l16) * NHID +
                                  kk * 32 + quad * 8);
#pragma unroll
      for (int j = 0; j < 8; j++) t[j] = (bf16)((float)t[j] * 0.015625f);
      qf[nt][kk] = t;
    }

  f32x4 oacc[4][2];
#pragma unroll
  for (int mt = 0; mt < 4; mt++)
#pragma unroll
    for (int nt = 0; nt < 2; nt++) oacc[mt][nt] = (f32x4)0.0f;
  float m_[2] = {-3.0e38f, -3.0e38f}, l_[2] = {0.0f, 0.0f};

  const bf16* kb = k + ((size_t)(b * SEQ)) * NHID + h * HDIM;
  const bf16* vb = vt + ((size_t)(b * NHID + h * HDIM)) * SEQ;

  const int sr0 = tid >> 3, sc0 = tid & 7;

  for (int kt = 0; kt < 16; kt++) {
    __syncthreads();   // prior-iter K/V LDS reads done before restage
#pragma unroll
    for (int i = 0; i < 2; i++) {
      int r = i * 32 + sr0;
      int cg = (sc0 ^ (r & 7)) * 8;
      bf16* lk = Ks + (size_t)(i * 256 + (tid & 192)) * 8;
      bf16* lv = Vs + (size_t)(i * 256 + (tid & 192)) * 8;
      GLD16(kb + (size_t)(kt * 64 + r) * NHID + cg, lk);
      GLD16(vb + (size_t)r * SEQ + kt * 64 + cg, lv);
    }
    __syncthreads();

    // ---- S^T = K @ Q^T  (already scaled via qf)
    f32x4 sacc[4][2];
#pragma unroll
    for (int mt = 0; mt < 4; mt++)
#pragma unroll
      for (int nt = 0; nt < 2; nt++) sacc[mt][nt] = (f32x4)0.0f;
#pragma unroll
    for (int kk = 0; kk < 2; kk++) {
      bf16x8 kf[4];
#pragma unroll
      for (int mt = 0; mt < 4; mt++) {
        int row = mt * 16 + l16;
        kf[mt] = *(const bf16x8*)(Ks + row * 64 +
                                  (((kk * 4 + quad) ^ (row & 7)) * 8));
      }
#pragma unroll
      for (int mt = 0; mt < 4; mt++)
#pragma unroll
        for (int nt = 0; nt < 2; nt++)
          sacc[mt][nt] = __builtin_amdgcn_mfma_f32_16x16x32_bf16(
              kf[mt], qf[nt][kk], sacc[mt][nt], 0, 0, 0);
    }

    // ---- online softmax (per q column = per (nt, l16))
    float alpha[2];
#pragma unroll
    for (int nt = 0; nt < 2; nt++) {
      float tm = -3.0e38f;
#pragma unroll
      for (int mt = 0; mt < 4; mt++)
#pragma unroll
        for (int r = 0; r < 4; r++) tm = fmaxf(tm, sacc[mt][nt][r]);
      tm = fmaxf(tm, __shfl_xor(tm, 16));
      tm = fmaxf(tm, __shfl_xor(tm, 32));
      float mn = fmaxf(m_[nt], tm);
      alpha[nt] = __expf(m_[nt] - mn);
      m_[nt] = mn;
      float ts = 0.0f;
#pragma unroll
      for (int mt = 0; mt < 4; mt++) {
        bf16x4 pv;
#pragma unroll
        for (int r = 0; r < 4; r++) {
          float p = __expf(sacc[mt][nt][r] - mn);
          ts += p;
          pv[r] = (bf16)p;
        }
        *(bf16x4*)(&Ps[wave][(nt * 16 + l16) * 72 + mt * 16 + quad * 4]) = pv;
      }
      ts += __shfl_xor(ts, 16);
      ts += __shfl_xor(ts, 32);
      l_[nt] = l_[nt] * alpha[nt] + ts;
    }
#pragma unroll
    for (int mt = 0; mt < 4; mt++)
#pragma unroll
      for (int nt = 0; nt < 2; nt++)
#pragma unroll
        for (int r = 0; r < 4; r++) oacc[mt][nt][r] *= alpha[nt];

    // Wave-level fence: Ps is wave-private. Memory clobber stops compiler
    // reordering (R2 post-mortem); lgkmcnt(0) waits for this wave's DS
    // writes to complete before the cross-lane reads below.
    __asm__ volatile("s_waitcnt lgkmcnt(0)" ::: "memory");

    // ---- O^T += V^T @ P^T
#pragma unroll
    for (int kk = 0; kk < 2; kk++) {
      bf16x8 vf[4], pf[2];
#pragma unroll
      for (int mt = 0; mt < 4; mt++) {
        int row = mt * 16 + l16;
        vf[mt] = *(const bf16x8*)(Vs + row * 64 +
                                  (((kk * 4 + quad) ^ (row & 7)) * 8));
      }
#pragma unroll
      for (int nt = 0; nt < 2; nt++)
        pf[nt] = *(const bf16x8*)(&Ps[wave][(nt * 16 + l16) * 72 +
                                            kk * 32 + quad * 8]);
#pragma unroll
      for (int mt = 0; mt < 4; mt++)
#pragma unroll
        for (int nt = 0; nt < 2; nt++)
          oacc[mt][nt] = __builtin_amdgcn_mfma_f32_16x16x32_bf16(
              vf[mt], pf[nt], oacc[mt][nt], 0, 0, 0);
    }
  }

  // ---- write O (un-transposing: per lane 4 consecutive hid cols)
#pragma unroll
  for (int nt = 0; nt < 2; nt++) {
    float rl = 1.0f / l_[nt];
#pragma unroll
    for (int mt = 0; mt < 4; mt++) {
      bf16x4 o4;
#pragma unroll
      for (int r = 0; r < 4; r++) o4[r] = (bf16)(oacc[mt][nt][r] * rl);
      *(bf16x4*)(o + ((size_t)(b * SEQ + qbase + nt * 16 + l16)) * NHID +
                 h * HDIM + mt * 16 + quad * 4) = o4;
    }
  }
}

// ---------------------------------------------------------------------------
// Workspace layout (bytes). Total ~136.2 MiB.
// wqT/wkT/wvT are contiguous -> one [3072][1024] QKV weight matrix.
// ---------------------------------------------------------------------------
#define OFF_CMOD 0u
#define OFF_WQT  196608u
#define OFF_WKT  (OFF_WQT + 2097152u)
#define OFF_WVT  (OFF_WKT + 2097152u)
#define OFF_WOT  (OFF_WVT + 2097152u)
#define OFF_W1T  (OFF_WOT + 2097152u)
#define OFF_W2T  (OFF_W1T + 8388608u)
#define OFF_X2   (OFF_W2T + 8388608u)
#define OFF_XM2  (OFF_X2  + 33554432u)
#define OFF_POOL (OFF_XM2 + 16777216u)
// pool (67.1 MB): xm @ +0, q @ +16M, k @ +32M, vt @ +48M.
// o aliases xm (dead after QKV GEMM); h aliases whole pool.

extern "C" void kernel_launch(void* const* d_in, const int* in_sizes, int n_in,
                              void* d_out, int out_size, void* d_ws, size_t ws_size,
                              hipStream_t stream)
{
  const float* x     = (const float*)d_in[0];
  const float* c     = (const float*)d_in[1];
  const float* w_ada = (const float*)d_in[2];
  const float* b_ada = (const float*)d_in[3];
  const float* wq = (const float*)d_in[4];  const float* bq = (const float*)d_in[5];
  const float* wk = (const float*)d_in[6];  const float* bk = (const float*)d_in[7];
  const float* wv = (const float*)d_in[8];  const float* bv = (const float*)d_in[9];
  const float* wo = (const float*)d_in[10]; const float* bo = (const float*)d_in[11];
  const float* w1 = (const float*)d_in[12]; const float* b1 = (const float*)d_in[13];
  const float* w2 = (const float*)d_in[14]; const float* b2 = (const float*)d_in[15];
  float* out = (float*)d_out;
  char* ws = (char*)d_ws;

  float* cmod = (float*)(ws + OFF_CMOD);
  bf16* wqT = (bf16*)(ws + OFF_WQT);     // base of contiguous [3072][1024]
  bf16* wkT = (bf16*)(ws + OFF_WKT);
  bf16* wvT = (bf16*)(ws + OFF_WVT);
  bf16* woT = (bf16*)(ws + OFF_WOT);
  bf16* w1T = (bf16*)(ws + OFF_W1T);
  bf16* w2T = (bf16*)(ws + OFF_W2T);
  float* x2 = (float*)(ws + OFF_X2);
  bf16* xm2 = (bf16*)(ws + OFF_XM2);
  bf16* xm  = (bf16*)(ws + OFF_POOL);
  bf16* qb  = (bf16*)(ws + OFF_POOL + 16777216u);
  bf16* kb  = (bf16*)(ws + OFF_POOL + 33554432u);
  bf16* vtb = (bf16*)(ws + OFF_POOL + 50331648u);
  bf16* ob  = xm;   // alias
  bf16* hb  = xm;   // alias (covers 64 MB of pool)

  // weight transposes (fp32 [K][N] -> bf16 [N][K]); 4×1024² batched
  TP4 tp;
  tp.s[0] = wq; tp.s[1] = wk; tp.s[2] = wv; tp.s[3] = wo;
  tp.d[0] = wqT; tp.d[1] = wkT; tp.d[2] = wvT; tp.d[3] = woT;
  transpose_conv4<<<dim3(32, 32, 4), 256, 0, stream>>>(tp);
  transpose_conv<<<dim3(128, 32), 256, 0, stream>>>(w1, w1T, 1024, 4096);
  transpose_conv<<<dim3(32, 128), 256, 0, stream>>>(w2, w2T, 4096, 1024);

  ada_kernel<<<dim3(24, 8), 256, 0, stream>>>(c, w_ada, b_ada, cmod);

  // ln1 + modulate (sh_msa @ 0, sc_msa @ 1024)
  ln_mod<<<8192, 256, 0, stream>>>(x, cmod, xm, 0, 1024);

  // fused QKV: N=3072; q/k normal, v transposed (vt[b][hid][seq])
  gemm_bt<5><<<dim3(24, 64), 256, 0, stream>>>(
      xm, wqT, bq, bk, bv, qb, kb, vtb, nullptr, nullptr, 0, nullptr,
      1024, 1024);

  attn_mfma<<<1024, 256, 0, stream>>>(qb, kb, vtb, ob);

  // x2 = x + g_msa * (o @ wo + bo)      (g_msa @ 2048)
  gemm_bt<1><<<dim3(8, 64), 256, 0, stream>>>(
      ob, woT, bo, nullptr, nullptr, nullptr, nullptr, nullptr, x2,
      cmod, 2048, x, 1024, 1024);

  // ln2 + modulate (sh_mlp @ 3072, sc_mlp @ 4096)
  ln_mod<<<8192, 256, 0, stream>>>(x2, cmod, xm2, 3072, 4096);

  // h = gelu(xm2 @ w1 + b1)   (tanh form)
  gemm_bt<2><<<dim3(32, 64), 256, 0, stream>>>(
      xm2, w1T, b1, nullptr, nullptr, hb, nullptr, nullptr, nullptr,
      nullptr, 0, nullptr, 4096, 1024);

  // out = x2 + g_mlp * (h @ w2 + b2)    (g_mlp @ 5120)
  gemm_bt<3><<<dim3(8, 64), 256, 0, stream>>>(
      hb, w2T, b2, nullptr, nullptr, nullptr, nullptr, nullptr, out,
      cmod, 5120, x2, 1024, 4096);
}

// Round 6
// 582.700 us; speedup vs baseline: 2.7046x; 1.0183x over previous
//
#include <hip/hip_runtime.h>
#include <hip/hip_bf16.h>
#include <cstdint>

// DiT block: B=8, N=1024, HID=1024, NH=16, HD=64, MLP=4096.
// R6: XCD swizzle REVERTED (R5 post-mortem: FETCH 78->139 MB, dur +3%).
// GEMM inner math switched to v_mfma_f32_32x32x16_bf16 (half the MFMA
// issues for the same FLOPs; A/B frag m=lane&31,k=(lane>>5)*8+j; C/D
// col=lane&31,row=(reg&3)+8*(reg>>2)+4*(lane>>5)). Staging still
// global_load_lds w=16 with XOR swizzle folded into the global address.
// Fused QKV GEMM, tanh-GELU, MFMA flash attention as R5.

typedef __bf16 bf16;
typedef __attribute__((ext_vector_type(8))) __bf16 bf16x8;
typedef __attribute__((ext_vector_type(4))) __bf16 bf16x4;
typedef __attribute__((ext_vector_type(4))) float f32x4;
typedef __attribute__((ext_vector_type(16))) float f32x16;

#define SEQ   1024
#define NHID  1024
#define NHEAD 16
#define HDIM  64
#define CMS   6144          // cmod row stride

// async 16B global->LDS: lds dest = wave-uniform base + lane*16
#define GLD16(gp, lp)                                                  \
  __builtin_amdgcn_global_load_lds(                                    \
      (const __attribute__((address_space(1))) void*)(gp),             \
      (__attribute__((address_space(3))) void*)(lp), 16, 0, 0)

// ---------------------------------------------------------------------------
// Batched transpose + fp32->bf16 convert for four 1024x1024 weights.
// ---------------------------------------------------------------------------
struct TP4 { const float* s[4]; bf16* d[4]; };

__global__ __launch_bounds__(256) void transpose_conv4(TP4 p)
{
  __shared__ float tile[32][33];
  const float* __restrict__ src = p.s[blockIdx.z];
  bf16* __restrict__ dst = p.d[blockIdx.z];
  int n0 = blockIdx.x * 32, k0 = blockIdx.y * 32;
  int tx = threadIdx.x & 31, ty = threadIdx.x >> 5;
#pragma unroll
  for (int i = 0; i < 32; i += 8)
    tile[ty + i][tx] = src[(size_t)(k0 + ty + i) * 1024 + n0 + tx];
  __syncthreads();
#pragma unroll
  for (int i = 0; i < 32; i += 8)
    dst[(size_t)(n0 + ty + i) * 1024 + k0 + tx] = (bf16)tile[tx][ty + i];
}

__global__ __launch_bounds__(256) void transpose_conv(
    const float* __restrict__ src, bf16* __restrict__ dst, int K, int N)
{
  __shared__ float tile[32][33];
  int n0 = blockIdx.x * 32, k0 = blockIdx.y * 32;
  int tx = threadIdx.x & 31, ty = threadIdx.x >> 5;
#pragma unroll
  for (int i = 0; i < 32; i += 8)
    tile[ty + i][tx] = src[(size_t)(k0 + ty + i) * N + n0 + tx];
  __syncthreads();
#pragma unroll
  for (int i = 0; i < 32; i += 8)
    dst[(size_t)(n0 + ty + i) * K + k0 + tx] = (bf16)tile[tx][ty + i];
}

// ---------------------------------------------------------------------------
// cmod = silu(c) @ w_ada + b_ada      c:[8][1024]  w_ada:[1024][6144]
// ---------------------------------------------------------------------------
__global__ __launch_bounds__(256) void ada_kernel(
    const float* __restrict__ c, const float* __restrict__ w_ada,
    const float* __restrict__ b_ada, float* __restrict__ cmod)
{
  __shared__ float cs[1024];
  int b = blockIdx.y;
  int col = blockIdx.x * 256 + threadIdx.x;
  for (int i = threadIdx.x; i < 1024; i += 256) {
    float cv = c[b * 1024 + i];
    cs[i] = cv / (1.0f + __expf(-cv));
  }
  __syncthreads();
  float acc = b_ada[col];
#pragma unroll 8
  for (int kk = 0; kk < 1024; kk++)
    acc += cs[kk] * w_ada[(size_t)kk * CMS + col];
  cmod[b * CMS + col] = acc;
}

// ---------------------------------------------------------------------------
// LayerNorm (no affine) + modulate -> bf16.  One block per row.
// ---------------------------------------------------------------------------
__global__ __launch_bounds__(256) void ln_mod(
    const float* __restrict__ x, const float* __restrict__ cmod,
    bf16* __restrict__ out, int sh_off, int sc_off)
{
  int row = blockIdx.x, b = row >> 10, tid = threadIdx.x;
  const float4* xr = (const float4*)(x + (size_t)row * NHID);
  float4 v = xr[tid];
  float s  = v.x + v.y + v.z + v.w;
  float s2 = v.x * v.x + v.y * v.y + v.z * v.z + v.w * v.w;
#pragma unroll
  for (int off = 32; off; off >>= 1) {
    s  += __shfl_xor(s, off);
    s2 += __shfl_xor(s2, off);
  }
  __shared__ float red1[4], red2[4];
  int wave = tid >> 6, lane = tid & 63;
  if (lane == 0) { red1[wave] = s; red2[wave] = s2; }
  __syncthreads();
  float S  = red1[0] + red1[1] + red1[2] + red1[3];
  float S2 = red2[0] + red2[1] + red2[2] + red2[3];
  float mean = S * (1.0f / NHID);
  float var  = S2 * (1.0f / NHID) - mean * mean;
  float rs   = rsqrtf(var + 1e-6f);
  const float4* shp = (const float4*)(cmod + b * CMS + sh_off);
  const float4* scp = (const float4*)(cmod + b * CMS + sc_off);
  float4 sh4 = shp[tid], sc4 = scp[tid];
  bf16x4 o4;
  o4[0] = (bf16)((v.x - mean) * rs * (1.0f + sc4.x) + sh4.x);
  o4[1] = (bf16)((v.y - mean) * rs * (1.0f + sc4.y) + sh4.y);
  o4[2] = (bf16)((v.z - mean) * rs * (1.0f + sc4.z) + sh4.z);
  o4[3] = (bf16)((v.w - mean) * rs * (1.0f + sc4.w) + sh4.w);
  *(bf16x4*)(out + (size_t)row * NHID + tid * 4) = o4;
}

// ---------------------------------------------------------------------------
// GEMM: C[M][N] = A[M][K](bf16) @ Bt[N][K](bf16)^T + bias, fused epilogues.
// 128x128 tile, BK=64, 4 waves (2x2 of 64x64), mfma 32x32x16 bf16
// (2x2 of 32x32 per wave). Staging: global_load_lds w=16, swizzled fetch.
// EPI: 1 = fp32 out = resid + gate*val (WO)
//      2 = bf16 tanh-gelu (W1)   3 = fp32 out = resid + gate*val (W2/final)
//      5 = fused QKV: col<1024 -> q, <2048 -> k, else v TRANSPOSED
// ---------------------------------------------------------------------------
template <int EPI>
__global__ __launch_bounds__(256) void gemm_bt(
    const bf16* __restrict__ A, const bf16* __restrict__ Bt,
    const float* __restrict__ bias, const float* __restrict__ bias2,
    const float* __restrict__ bias3,
    bf16* __restrict__ outb, bf16* __restrict__ outb2,
    bf16* __restrict__ outb3, float* __restrict__ outf,
    const float* __restrict__ cmod, int gate_off,
    const float* __restrict__ resid,
    int N, int K)
{
  __shared__ __align__(16) bf16 As[128 * 64];
  __shared__ __align__(16) bf16 Bs[128 * 64];
  const int tid = threadIdx.x;
  const int bm = blockIdx.y * 128, bn = blockIdx.x * 128;

  const int wave = tid >> 6, lane = tid & 63;
  const int l32 = lane & 31, half = lane >> 5;
  const int wm = (wave >> 1) * 64, wn = (wave & 1) * 64;

  const int sr = tid >> 3;                 // staging row for i=0
  const int sc = tid & 7;

  f32x16 acc[2][2];
#pragma unroll
  for (int i = 0; i < 2; i++)
#pragma unroll
    for (int j = 0; j < 2; j++) acc[i][j] = (f32x16)0.0f;

  for (int k0 = 0; k0 < K; k0 += 64) {
#pragma unroll
    for (int i = 0; i < 4; i++) {
      int r = i * 32 + sr;
      int cg = (sc ^ (r & 7)) * 8;
      bf16* lbase_a = As + (size_t)(i * 256 + (tid & 192)) * 8;
      bf16* lbase_b = Bs + (size_t)(i * 256 + (tid & 192)) * 8;
      GLD16(A  + (size_t)(bm + r) * K + k0 + cg, lbase_a);
      GLD16(Bt + (size_t)(bn + r) * K + k0 + cg, lbase_b);
    }
    __syncthreads();
#pragma unroll
    for (int kk = 0; kk < 4; kk++) {       // k-step of 16
      int cc = kk * 2 + half;              // chunk col for this lane
      bf16x8 af[2], bfr[2];
#pragma unroll
      for (int t = 0; t < 2; t++) {
        int ra = wm + t * 32 + l32;
        int rb = wn + t * 32 + l32;
        af[t]  = *(const bf16x8*)(As + ra * 64 + ((cc ^ (ra & 7)) * 8));
        bfr[t] = *(const bf16x8*)(Bs + rb * 64 + ((cc ^ (rb & 7)) * 8));
      }
#pragma unroll
      for (int mt = 0; mt < 2; mt++)
#pragma unroll
        for (int nt = 0; nt < 2; nt++)
          acc[mt][nt] = __builtin_amdgcn_mfma_f32_32x32x16_bf16(
              af[mt], bfr[nt], acc[mt][nt], 0, 0, 0);
    }
    __syncthreads();
  }

  // block-uniform epilogue select for EPI==5
  const int sel = bn >> 10;
  const float* bp = (EPI == 5)
      ? ((sel == 0) ? bias : (sel == 1) ? bias2 : bias3) : bias;
  bf16* qk_out = (EPI == 5) ? ((sel == 0) ? outb : outb2) : outb;

#pragma unroll
  for (int mt = 0; mt < 2; mt++) {
#pragma unroll
    for (int nt = 0; nt < 2; nt++) {
      int col = bn + wn + nt * 32 + l32;
      int colq = col & 1023;
      float bcol = (EPI == 5) ? bp[colq] : bias[col];
#pragma unroll
      for (int g = 0; g < 4; g++) {
        int row0 = bm + wm + mt * 32 + g * 8 + half * 4;
        if (EPI == 5 && sel == 2) {
          // V: transposed write vt[b][hid][seq]; 4 consecutive seq rows
          bf16x4 o4;
#pragma unroll
          for (int r = 0; r < 4; r++)
            o4[r] = (bf16)(acc[mt][nt][g * 4 + r] + bcol);
          int bb = row0 >> 10;
          *(bf16x4*)(outb3 + ((size_t)bb * NHID + colq) * SEQ +
                     (row0 & 1023)) = o4;
        } else if (EPI == 5) {
#pragma unroll
          for (int r = 0; r < 4; r++)
            qk_out[(size_t)(row0 + r) * 1024 + colq] =
                (bf16)(acc[mt][nt][g * 4 + r] + bcol);
        } else {
#pragma unroll
          for (int r = 0; r < 4; r++) {
            int row = row0 + r;
            float val = acc[mt][nt][g * 4 + r] + bcol;
            if (EPI == 1 || EPI == 3) {
              int bb = row >> 10;
              float gg = cmod[bb * CMS + gate_off + col];
              outf[(size_t)row * N + col] =
                  resid[(size_t)row * N + col] + gg * val;
            } else {  // EPI == 2: tanh-form GELU
              float u2 = 2.0f * val * (0.7978845608f +
                                       0.0356774081f * val * val);
              float e = __expf(u2);
              float th = 1.0f - 2.0f / (e + 1.0f);
              outb[(size_t)row * N + col] = (bf16)(0.5f * val * (1.0f + th));
            }
          }
        }
      }
    }
  }
}

// ---------------------------------------------------------------------------
// MFMA flash attention (unchanged from R5 — passing).
// ---------------------------------------------------------------------------
__global__ __launch_bounds__(256) void attn_mfma(
    const bf16* __restrict__ q, const bf16* __restrict__ k,
    const bf16* __restrict__ vt, bf16* __restrict__ o)
{
  __shared__ __align__(16) bf16 Ks[64 * 64];
  __shared__ __align__(16) bf16 Vs[64 * 64];
  __shared__ __align__(16) bf16 Ps[4][32 * 72];   // [wave][qloc][key] stride 72

  int bid = blockIdx.x;
  int qt = bid & 7, h = (bid >> 3) & 15, b = bid >> 7;
  int tid = threadIdx.x, wave = tid >> 6, lane = tid & 63;
  int quad = lane >> 4, l16 = lane & 15;
  int qbase = qt * 128 + wave * 32;

  bf16x8 qf[2][2];
  const bf16* qp = q + ((size_t)(b * SEQ + qbase)) * NHID + h * HDIM;
#pragma unroll
  for (int nt = 0; nt < 2; nt++)
#pragma unroll
    for (int kk = 0; kk < 2; kk++) {
      bf16x8 t = *(const bf16x8*)(qp + (size_t)(nt * 16 + l16) * NHID +
                                  kk * 32 + quad * 8);
#pragma unroll
      for (int j = 0; j < 8; j++) t[j] = (bf16)((float)t[j] * 0.015625f);
      qf[nt][kk] = t;
    }

  f32x4 oacc[4][2];
#pragma unroll
  for (int mt = 0; mt < 4; mt++)
#pragma unroll
    for (int nt = 0; nt < 2; nt++) oacc[mt][nt] = (f32x4)0.0f;
  float m_[2] = {-3.0e38f, -3.0e38f}, l_[2] = {0.0f, 0.0f};

  const bf16* kb = k + ((size_t)(b * SEQ)) * NHID + h * HDIM;
  const bf16* vb = vt + ((size_t)(b * NHID + h * HDIM)) * SEQ;

  const int sr0 = tid >> 3, sc0 = tid & 7;

  for (int kt = 0; kt < 16; kt++) {
    __syncthreads();   // prior-iter K/V LDS reads done before restage
#pragma unroll
    for (int i = 0; i < 2; i++) {
      int r = i * 32 + sr0;
      int cg = (sc0 ^ (r & 7)) * 8;
      bf16* lk = Ks + (size_t)(i * 256 + (tid & 192)) * 8;
      bf16* lv = Vs + (size_t)(i * 256 + (tid & 192)) * 8;
      GLD16(kb + (size_t)(kt * 64 + r) * NHID + cg, lk);
      GLD16(vb + (size_t)r * SEQ + kt * 64 + cg, lv);
    }
    __syncthreads();

    // ---- S^T = K @ Q^T  (already scaled via qf)
    f32x4 sacc[4][2];
#pragma unroll
    for (int mt = 0; mt < 4; mt++)
#pragma unroll
      for (int nt = 0; nt < 2; nt++) sacc[mt][nt] = (f32x4)0.0f;
#pragma unroll
    for (int kk = 0; kk < 2; kk++) {
      bf16x8 kf[4];
#pragma unroll
      for (int mt = 0; mt < 4; mt++) {
        int row = mt * 16 + l16;
        kf[mt] = *(const bf16x8*)(Ks + row * 64 +
                                  (((kk * 4 + quad) ^ (row & 7)) * 8));
      }
#pragma unroll
      for (int mt = 0; mt < 4; mt++)
#pragma unroll
        for (int nt = 0; nt < 2; nt++)
          sacc[mt][nt] = __builtin_amdgcn_mfma_f32_16x16x32_bf16(
              kf[mt], qf[nt][kk], sacc[mt][nt], 0, 0, 0);
    }

    // ---- online softmax (per q column = per (nt, l16))
    float alpha[2];
#pragma unroll
    for (int nt = 0; nt < 2; nt++) {
      float tm = -3.0e38f;
#pragma unroll
      for (int mt = 0; mt < 4; mt++)
#pragma unroll
        for (int r = 0; r < 4; r++) tm = fmaxf(tm, sacc[mt][nt][r]);
      tm = fmaxf(tm, __shfl_xor(tm, 16));
      tm = fmaxf(tm, __shfl_xor(tm, 32));
      float mn = fmaxf(m_[nt], tm);
      alpha[nt] = __expf(m_[nt] - mn);
      m_[nt] = mn;
      float ts = 0.0f;
#pragma unroll
      for (int mt = 0; mt < 4; mt++) {
        bf16x4 pv;
#pragma unroll
        for (int r = 0; r < 4; r++) {
          float p = __expf(sacc[mt][nt][r] - mn);
          ts += p;
          pv[r] = (bf16)p;
        }
        *(bf16x4*)(&Ps[wave][(nt * 16 + l16) * 72 + mt * 16 + quad * 4]) = pv;
      }
      ts += __shfl_xor(ts, 16);
      ts += __shfl_xor(ts, 32);
      l_[nt] = l_[nt] * alpha[nt] + ts;
    }
#pragma unroll
    for (int mt = 0; mt < 4; mt++)
#pragma unroll
      for (int nt = 0; nt < 2; nt++)
#pragma unroll
        for (int r = 0; r < 4; r++) oacc[mt][nt][r] *= alpha[nt];

    // Wave-level fence: Ps is wave-private (R2/R5 post-mortems).
    __asm__ volatile("s_waitcnt lgkmcnt(0)" ::: "memory");

    // ---- O^T += V^T @ P^T
#pragma unroll
    for (int kk = 0; kk < 2; kk++) {
      bf16x8 vf[4], pf[2];
#pragma unroll
      for (int mt = 0; mt < 4; mt++) {
        int row = mt * 16 + l16;
        vf[mt] = *(const bf16x8*)(Vs + row * 64 +
                                  (((kk * 4 + quad) ^ (row & 7)) * 8));
      }
#pragma unroll
      for (int nt = 0; nt < 2; nt++)
        pf[nt] = *(const bf16x8*)(&Ps[wave][(nt * 16 + l16) * 72 +
                                            kk * 32 + quad * 8]);
#pragma unroll
      for (int mt = 0; mt < 4; mt++)
#pragma unroll
        for (int nt = 0; nt < 2; nt++)
          oacc[mt][nt] = __builtin_amdgcn_mfma_f32_16x16x32_bf16(
              vf[mt], pf[nt], oacc[mt][nt], 0, 0, 0);
    }
  }

  // ---- write O (un-transposing: per lane 4 consecutive hid cols)
#pragma unroll
  for (int nt = 0; nt < 2; nt++) {
    float rl = 1.0f / l_[nt];
#pragma unroll
    for (int mt = 0; mt < 4; mt++) {
      bf16x4 o4;
#pragma unroll
      for (int r = 0; r < 4; r++) o4[r] = (bf16)(oacc[mt][nt][r] * rl);
      *(bf16x4*)(o + ((size_t)(b * SEQ + qbase + nt * 16 + l16)) * NHID +
                 h * HDIM + mt * 16 + quad * 4) = o4;
    }
  }
}

// ---------------------------------------------------------------------------
// Workspace layout (bytes). Total ~136.2 MiB.
// wqT/wkT/wvT contiguous -> one [3072][1024] QKV weight matrix.
// ---------------------------------------------------------------------------
#define OFF_CMOD 0u
#define OFF_WQT  196608u
#define OFF_WKT  (OFF_WQT + 2097152u)
#define OFF_WVT  (OFF_WKT + 2097152u)
#define OFF_WOT  (OFF_WVT + 2097152u)
#define OFF_W1T  (OFF_WOT + 2097152u)
#define OFF_W2T  (OFF_W1T + 8388608u)
#define OFF_X2   (OFF_W2T + 8388608u)
#define OFF_XM2  (OFF_X2  + 33554432u)
#define OFF_POOL (OFF_XM2 + 16777216u)
// pool (67.1 MB): xm @ +0, q @ +16M, k @ +32M, vt @ +48M.
// o aliases xm (dead after QKV GEMM); h aliases whole pool.

extern "C" void kernel_launch(void* const* d_in, const int* in_sizes, int n_in,
                              void* d_out, int out_size, void* d_ws, size_t ws_size,
                              hipStream_t stream)
{
  const float* x     = (const float*)d_in[0];
  const float* c     = (const float*)d_in[1];
  const float* w_ada = (const float*)d_in[2];
  const float* b_ada = (const float*)d_in[3];
  const float* wq = (const float*)d_in[4];  const float* bq = (const float*)d_in[5];
  const float* wk = (const float*)d_in[6];  const float* bk = (const float*)d_in[7];
  const float* wv = (const float*)d_in[8];  const float* bv = (const float*)d_in[9];
  const float* wo = (const float*)d_in[10]; const float* bo = (const float*)d_in[11];
  const float* w1 = (const float*)d_in[12]; const float* b1 = (const float*)d_in[13];
  const float* w2 = (const float*)d_in[14]; const float* b2 = (const float*)d_in[15];
  float* out = (float*)d_out;
  char* ws = (char*)d_ws;

  float* cmod = (float*)(ws + OFF_CMOD);
  bf16* wqT = (bf16*)(ws + OFF_WQT);     // base of contiguous [3072][1024]
  bf16* wkT = (bf16*)(ws + OFF_WKT);
  bf16* wvT = (bf16*)(ws + OFF_WVT);
  bf16* woT = (bf16*)(ws + OFF_WOT);
  bf16* w1T = (bf16*)(ws + OFF_W1T);
  bf16* w2T = (bf16*)(ws + OFF_W2T);
  float* x2 = (float*)(ws + OFF_X2);
  bf16* xm2 = (bf16*)(ws + OFF_XM2);
  bf16* xm  = (bf16*)(ws + OFF_POOL);
  bf16* qb  = (bf16*)(ws + OFF_POOL + 16777216u);
  bf16* kb  = (bf16*)(ws + OFF_POOL + 33554432u);
  bf16* vtb = (bf16*)(ws + OFF_POOL + 50331648u);
  bf16* ob  = xm;   // alias
  bf16* hb  = xm;   // alias (covers 64 MB of pool)

  TP4 tp;
  tp.s[0] = wq; tp.s[1] = wk; tp.s[2] = wv; tp.s[3] = wo;
  tp.d[0] = wqT; tp.d[1] = wkT; tp.d[2] = wvT; tp.d[3] = woT;
  transpose_conv4<<<dim3(32, 32, 4), 256, 0, stream>>>(tp);
  transpose_conv<<<dim3(128, 32), 256, 0, stream>>>(w1, w1T, 1024, 4096);
  transpose_conv<<<dim3(32, 128), 256, 0, stream>>>(w2, w2T, 4096, 1024);

  ada_kernel<<<dim3(24, 8), 256, 0, stream>>>(c, w_ada, b_ada, cmod);

  // ln1 + modulate (sh_msa @ 0, sc_msa @ 1024)
  ln_mod<<<8192, 256, 0, stream>>>(x, cmod, xm, 0, 1024);

  // fused QKV: N=3072; q/k normal, v transposed (vt[b][hid][seq])
  gemm_bt<5><<<dim3(24, 64), 256, 0, stream>>>(
      xm, wqT, bq, bk, bv, qb, kb, vtb, nullptr, nullptr, 0, nullptr,
      1024, 1024);

  attn_mfma<<<1024, 256, 0, stream>>>(qb, kb, vtb, ob);

  // x2 = x + g_msa * (o @ wo + bo)      (g_msa @ 2048)
  gemm_bt<1><<<dim3(8, 64), 256, 0, stream>>>(
      ob, woT, bo, nullptr, nullptr, nullptr, nullptr, nullptr, x2,
      cmod, 2048, x, 1024, 1024);

  // ln2 + modulate (sh_mlp @ 3072, sc_mlp @ 4096)
  ln_mod<<<8192, 256, 0, stream>>>(x2, cmod, xm2, 3072, 4096);

  // h = gelu(xm2 @ w1 + b1)   (tanh form)
  gemm_bt<2><<<dim3(32, 64), 256, 0, stream>>>(
      xm2, w1T, b1, nullptr, nullptr, hb, nullptr, nullptr, nullptr,
      nullptr, 0, nullptr, 4096, 1024);

  // out = x2 + g_mlp * (h @ w2 + b2)    (g_mlp @ 5120)
  gemm_bt<3><<<dim3(8, 64), 256, 0, stream>>>(
      hb, w2T, b2, nullptr, nullptr, nullptr, nullptr, nullptr, out,
      cmod, 5120, x2, 1024, 4096);
}